// Round 1
// baseline (1637.841 us; speedup 1.0000x reference)
//
#include <hip/hip_runtime.h>

#define TT 8192   // tokens
#define HD 1024   // hidden
#define ID 2816   // intermediate
#define NE 8      // experts

typedef __attribute__((ext_vector_type(8))) short short8;
typedef __attribute__((ext_vector_type(4))) float f32x4;

__device__ __forceinline__ unsigned int pack_bf2(float lo, float hi) {
  unsigned int ul = __builtin_bit_cast(unsigned int, lo) + 0x8000u;
  unsigned int uh = __builtin_bit_cast(unsigned int, hi) + 0x8000u;
  return (uh & 0xffff0000u) | (ul >> 16);
}

__device__ __forceinline__ unsigned short f2bf(float f) {
  unsigned int u = __builtin_bit_cast(unsigned int, f);
  return (unsigned short)((u + 0x8000u) >> 16);
}

// ---------------- Router: fp32 logits, top-2, renormalized weights ----------
__global__ __launch_bounds__(256) void router_kernel(
    const float* __restrict__ x, const float* __restrict__ wr,
    int* __restrict__ top2i, float* __restrict__ top2w)
{
  int tid  = threadIdx.x;
  int lane = tid & 63;
  int t    = blockIdx.x * 4 + (tid >> 6);   // wave per token

  const float4* xp = (const float4*)(x + (size_t)t * HD + lane * 16);
  float4 xv[4];
  #pragma unroll
  for (int j = 0; j < 4; ++j) xv[j] = xp[j];

  float acc[NE];
  #pragma unroll
  for (int e = 0; e < NE; ++e) {
    const float4* wp = (const float4*)(wr + (size_t)e * HD + lane * 16);
    float s = 0.f;
    #pragma unroll
    for (int j = 0; j < 4; ++j) {
      float4 w = wp[j];
      s += xv[j].x * w.x + xv[j].y * w.y + xv[j].z * w.z + xv[j].w * w.w;
    }
    acc[e] = s;
  }
  #pragma unroll
  for (int d = 1; d < 64; d <<= 1) {
    #pragma unroll
    for (int e = 0; e < NE; ++e) acc[e] += __shfl_xor(acc[e], d, 64);
  }
  // top-2 by logit (softmax is monotone); ties -> lowest index, matching top_k
  int   i0 = 0; float m0 = acc[0];
  #pragma unroll
  for (int e = 1; e < NE; ++e) if (acc[e] > m0) { m0 = acc[e]; i0 = e; }
  int   i1 = -1; float m1 = -3.4e38f;
  #pragma unroll
  for (int e = 0; e < NE; ++e) if (e != i0 && acc[e] > m1) { m1 = acc[e]; i1 = e; }

  float e1 = __expf(m1 - m0);
  float w0 = 1.f / (1.f + e1);  // = p0/(p0+p1)
  float w1 = e1 * w0;

  if (lane == 0) {
    top2i[2 * t]     = i0;  top2i[2 * t + 1] = i1;
    top2w[2 * t]     = w0;  top2w[2 * t + 1] = w1;
  }
}

// ---------------- Count + exclusive scan (1 block) --------------------------
__global__ __launch_bounds__(256) void count_scan_kernel(
    const int* __restrict__ top2i,
    int* __restrict__ counts, int* __restrict__ offsets, int* __restrict__ cursors)
{
  __shared__ int s_cnt[NE];
  int tid = threadIdx.x;
  if (tid < NE) s_cnt[tid] = 0;
  __syncthreads();

  int c0=0,c1=0,c2=0,c3=0,c4=0,c5=0,c6=0,c7=0;
  for (int t = tid; t < TT; t += 256) {
    int e0 = top2i[2 * t], e1 = top2i[2 * t + 1];
    c0 += __popcll(__ballot(e0 == 0)) + __popcll(__ballot(e1 == 0));
    c1 += __popcll(__ballot(e0 == 1)) + __popcll(__ballot(e1 == 1));
    c2 += __popcll(__ballot(e0 == 2)) + __popcll(__ballot(e1 == 2));
    c3 += __popcll(__ballot(e0 == 3)) + __popcll(__ballot(e1 == 3));
    c4 += __popcll(__ballot(e0 == 4)) + __popcll(__ballot(e1 == 4));
    c5 += __popcll(__ballot(e0 == 5)) + __popcll(__ballot(e1 == 5));
    c6 += __popcll(__ballot(e0 == 6)) + __popcll(__ballot(e1 == 6));
    c7 += __popcll(__ballot(e0 == 7)) + __popcll(__ballot(e1 == 7));
  }
  if ((tid & 63) == 0) {  // one lane per wave adds whole-wave totals
    atomicAdd(&s_cnt[0], c0); atomicAdd(&s_cnt[1], c1);
    atomicAdd(&s_cnt[2], c2); atomicAdd(&s_cnt[3], c3);
    atomicAdd(&s_cnt[4], c4); atomicAdd(&s_cnt[5], c5);
    atomicAdd(&s_cnt[6], c6); atomicAdd(&s_cnt[7], c7);
  }
  __syncthreads();
  if (tid == 0) {
    int run = 0;
    #pragma unroll
    for (int e = 0; e < NE; ++e) {
      counts[e]  = s_cnt[e];
      offsets[e] = run;
      cursors[e] = run;
      run += s_cnt[e];
    }
    offsets[NE] = run;  // == 2*TT
  }
}

// ---------------- Placement into packed slots (wave-aggregated atomics) -----
__global__ __launch_bounds__(256) void place_kernel(
    const int* __restrict__ top2i, const float* __restrict__ top2w,
    int* __restrict__ cursors,
    int* __restrict__ token_map, float* __restrict__ slot_w)
{
  int tid  = threadIdx.x;
  int lane = tid & 63;
  int t    = blockIdx.x * 256 + tid;

  #pragma unroll
  for (int k = 0; k < 2; ++k) {
    int   e = top2i[2 * t + k];
    float w = top2w[2 * t + k];
    #pragma unroll
    for (int ee = 0; ee < NE; ++ee) {
      unsigned long long m = __ballot(e == ee);
      if (e == ee) {
        int leader = __ffsll((long long)m) - 1;
        int pre    = __popcll(m & ((1ull << lane) - 1ull));
        int base   = 0;
        if (lane == leader) base = atomicAdd(&cursors[ee], (int)__popcll(m));
        base = __shfl(base, leader, 64);
        token_map[base + pre] = t;
        slot_w[base + pre]    = w;
      }
    }
  }
}

// ---------------- LDS staging helpers (XOR-swizzled, T2) --------------------
// tile layout: [128 rows][64 bf16], row stride 128 B, byte ^= (row&7)<<4
__device__ __forceinline__ void stage_f32(short* lds, int row, int colh, const float* src) {
  char* base = (char*)lds + row * 128;
  unsigned int swz = (unsigned int)((row & 7) << 4);
  if (src) {
    const float4* s4 = (const float4*)src;
    #pragma unroll
    for (int i = 0; i < 4; ++i) {
      float4 a = s4[2 * i], b = s4[2 * i + 1];
      uint4 v;
      v.x = pack_bf2(a.x, a.y); v.y = pack_bf2(a.z, a.w);
      v.z = pack_bf2(b.x, b.y); v.w = pack_bf2(b.z, b.w);
      *(uint4*)(base + (((unsigned int)((colh + i * 8) * 2)) ^ swz)) = v;
    }
  } else {
    uint4 z; z.x = z.y = z.z = z.w = 0u;
    #pragma unroll
    for (int i = 0; i < 4; ++i)
      *(uint4*)(base + (((unsigned int)((colh + i * 8) * 2)) ^ swz)) = z;
  }
}

__device__ __forceinline__ void stage_bf16(short* lds, int row, int colh, const unsigned short* src) {
  char* base = (char*)lds + row * 128;
  unsigned int swz = (unsigned int)((row & 7) << 4);
  if (src) {
    const uint4* s4 = (const uint4*)src;
    #pragma unroll
    for (int i = 0; i < 4; ++i)
      *(uint4*)(base + (((unsigned int)((colh + i * 8) * 2)) ^ swz)) = s4[i];
  } else {
    uint4 z; z.x = z.y = z.z = z.w = 0u;
    #pragma unroll
    for (int i = 0; i < 4; ++i)
      *(uint4*)(base + (((unsigned int)((colh + i * 8) * 2)) ^ swz)) = z;
  }
}

__device__ __forceinline__ short8 ldfrag(const short* lds, int row, int kc) {
  unsigned int off = (unsigned int)(row * 128) +
                     (((unsigned int)(kc * 2)) ^ ((unsigned int)((row & 7) << 4)));
  return *(const short8*)((const char*)lds + off);
}

// ---------------- GEMM1: act[slot,i] = silu(x@wg^T) * (x@wu^T)  (bf16 MFMA) -
__global__ __launch_bounds__(256, 2) void gemm1_kernel(
    const float* __restrict__ x,
    const float* __restrict__ w_gate, const float* __restrict__ w_up,
    const int* __restrict__ counts, const int* __restrict__ offsets,
    const int* __restrict__ token_map, unsigned short* __restrict__ act)
{
  int e   = blockIdx.z;
  int cnt = counts[e];
  int t0  = blockIdx.x * 128;
  if (t0 >= cnt) return;
  int i0  = blockIdx.y * 128;
  int off = offsets[e];

  __shared__ short sA[128 * 64];
  __shared__ short sG[128 * 64];
  __shared__ short sU[128 * 64];

  int tid  = threadIdx.x;
  int lane = tid & 63;
  int wid  = tid >> 6;
  int wr0  = (wid >> 1) * 64;
  int wc0  = (wid & 1) * 64;

  int srow = tid >> 1;          // staging row 0..127
  int colh = (tid & 1) * 32;    // staging col half (in elements)

  const float* aptr = nullptr;
  int tr = t0 + srow;
  if (tr < cnt) aptr = x + (size_t)token_map[off + tr] * HD + colh;
  const float* gptr = w_gate + (size_t)e * ID * HD + (size_t)(i0 + srow) * HD + colh;
  const float* uptr = w_up   + (size_t)e * ID * HD + (size_t)(i0 + srow) * HD + colh;

  f32x4 zf = {0.f, 0.f, 0.f, 0.f};
  f32x4 accg[4][4], accu[4][4];
  #pragma unroll
  for (int m = 0; m < 4; ++m)
    #pragma unroll
    for (int n = 0; n < 4; ++n) { accg[m][n] = zf; accu[m][n] = zf; }

  for (int kt = 0; kt < HD / 64; ++kt) {
    int k0 = kt * 64;
    if (kt) __syncthreads();
    stage_f32(sA, srow, colh, aptr ? aptr + k0 : nullptr);
    stage_f32(sG, srow, colh, gptr + k0);
    stage_f32(sU, srow, colh, uptr + k0);
    __syncthreads();
    #pragma unroll
    for (int ks = 0; ks < 2; ++ks) {
      int kc = ks * 32 + (lane >> 4) * 8;
      short8 af[4], gf[4], uf[4];
      #pragma unroll
      for (int m = 0; m < 4; ++m) af[m] = ldfrag(sA, wr0 + m * 16 + (lane & 15), kc);
      #pragma unroll
      for (int n = 0; n < 4; ++n) {
        gf[n] = ldfrag(sG, wc0 + n * 16 + (lane & 15), kc);
        uf[n] = ldfrag(sU, wc0 + n * 16 + (lane & 15), kc);
      }
      #pragma unroll
      for (int m = 0; m < 4; ++m)
        #pragma unroll
        for (int n = 0; n < 4; ++n) {
          accg[m][n] = __builtin_amdgcn_mfma_f32_16x16x32_bf16(af[m], gf[n], accg[m][n], 0, 0, 0);
          accu[m][n] = __builtin_amdgcn_mfma_f32_16x16x32_bf16(af[m], uf[n], accu[m][n], 0, 0, 0);
        }
    }
  }

  #pragma unroll
  for (int m = 0; m < 4; ++m) {
    #pragma unroll
    for (int r = 0; r < 4; ++r) {
      int row = wr0 + m * 16 + ((lane >> 4) << 2) + r;
      int tr2 = t0 + row;
      if (tr2 >= cnt) continue;
      size_t base = (size_t)(off + tr2) * ID + (size_t)(i0 + wc0 + (lane & 15));
      #pragma unroll
      for (int n = 0; n < 4; ++n) {
        float g = accg[m][n][r];
        float u = accu[m][n][r];
        float h = g * u / (1.f + __expf(-g));   // silu(g)*u
        act[base + n * 16] = f2bf(h);
      }
    }
  }
}

// ---------------- GEMM2: out[token,h] += w_slot * (act @ w_down^T) ----------
__global__ __launch_bounds__(256, 2) void gemm2_kernel(
    const unsigned short* __restrict__ act, const float* __restrict__ w_down,
    const int* __restrict__ counts, const int* __restrict__ offsets,
    const int* __restrict__ token_map, const float* __restrict__ slot_w,
    float* __restrict__ out)
{
  int e   = blockIdx.z;
  int cnt = counts[e];
  int t0  = blockIdx.x * 128;
  if (t0 >= cnt) return;
  int h0  = blockIdx.y * 128;
  int off = offsets[e];

  __shared__ short sA[128 * 64];
  __shared__ short sB[128 * 64];

  int tid  = threadIdx.x;
  int lane = tid & 63;
  int wid  = tid >> 6;
  int wr0  = (wid >> 1) * 64;
  int wc0  = (wid & 1) * 64;

  int srow = tid >> 1;
  int colh = (tid & 1) * 32;

  const unsigned short* aptr = nullptr;
  int tr = t0 + srow;
  if (tr < cnt) aptr = act + (size_t)(off + tr) * ID + colh;
  const float* bptr = w_down + (size_t)e * HD * ID + (size_t)(h0 + srow) * ID + colh;

  f32x4 zf = {0.f, 0.f, 0.f, 0.f};
  f32x4 acc[4][4];
  #pragma unroll
  for (int m = 0; m < 4; ++m)
    #pragma unroll
    for (int n = 0; n < 4; ++n) acc[m][n] = zf;

  for (int kt = 0; kt < ID / 64; ++kt) {
    int k0 = kt * 64;
    if (kt) __syncthreads();
    stage_bf16(sA, srow, colh, aptr ? aptr + k0 : nullptr);
    stage_f32(sB, srow, colh, bptr + k0);
    __syncthreads();
    #pragma unroll
    for (int ks = 0; ks < 2; ++ks) {
      int kc = ks * 32 + (lane >> 4) * 8;
      short8 af[4], bf[4];
      #pragma unroll
      for (int m = 0; m < 4; ++m) af[m] = ldfrag(sA, wr0 + m * 16 + (lane & 15), kc);
      #pragma unroll
      for (int n = 0; n < 4; ++n) bf[n] = ldfrag(sB, wc0 + n * 16 + (lane & 15), kc);
      #pragma unroll
      for (int m = 0; m < 4; ++m)
        #pragma unroll
        for (int n = 0; n < 4; ++n)
          acc[m][n] = __builtin_amdgcn_mfma_f32_16x16x32_bf16(af[m], bf[n], acc[m][n], 0, 0, 0);
    }
  }

  #pragma unroll
  for (int m = 0; m < 4; ++m) {
    #pragma unroll
    for (int r = 0; r < 4; ++r) {
      int row = wr0 + m * 16 + ((lane >> 4) << 2) + r;
      int tr2 = t0 + row;
      if (tr2 >= cnt) continue;
      int slot = off + tr2;
      float w  = slot_w[slot];
      float* obase = out + (size_t)token_map[slot] * HD + (size_t)(h0 + wc0 + (lane & 15));
      #pragma unroll
      for (int n = 0; n < 4; ++n)
        atomicAdd(obase + n * 16, acc[m][n][r] * w);   // 2 commutative adds/elem -> deterministic
    }
  }
}

// ---------------- launch ----------------------------------------------------
extern "C" void kernel_launch(void* const* d_in, const int* in_sizes, int n_in,
                              void* d_out, int out_size, void* d_ws, size_t ws_size,
                              hipStream_t stream) {
  const float* x        = (const float*)d_in[0];
  const float* w_router = (const float*)d_in[1];
  const float* w_gate   = (const float*)d_in[2];
  const float* w_up     = (const float*)d_in[3];
  const float* w_down   = (const float*)d_in[4];

  char* ws = (char*)d_ws;
  int*            top2i   = (int*)(ws);                          // 64 KB
  float*          top2w   = (float*)(ws + 65536);                // 64 KB
  int*            counts  = (int*)(ws + 131072);                 // 32 B
  int*            offsets = (int*)(ws + 131072 + 64);            // 36 B
  int*            cursors = (int*)(ws + 131072 + 128);           // 32 B
  int*            tmap    = (int*)(ws + 131072 + 256);           // 64 KB
  float*          slotw   = (float*)(ws + 131072 + 256 + 65536); // 64 KB
  unsigned short* act     = (unsigned short*)(ws + 524288);      // 2T x I bf16 = 92.3 MB

  hipMemsetAsync(d_out, 0, (size_t)out_size * sizeof(float), stream);
  router_kernel<<<TT / 4, 256, 0, stream>>>(x, w_router, top2i, top2w);
  count_scan_kernel<<<1, 256, 0, stream>>>(top2i, counts, offsets, cursors);
  place_kernel<<<TT / 256, 256, 0, stream>>>(top2i, top2w, cursors, tmap, slotw);
  gemm1_kernel<<<dim3(64, 22, NE), 256, 0, stream>>>(x, w_gate, w_up, counts, offsets, tmap, act);
  gemm2_kernel<<<dim3(64, 8, NE), 256, 0, stream>>>(act, w_down, counts, offsets, tmap, slotw, (float*)d_out);
}

// Round 2
// 897.603 us; speedup vs baseline: 1.8247x; 1.8247x over previous
//
#include <hip/hip_runtime.h>

#define TT 8192   // tokens
#define HD 1024   // hidden
#define ID 2816   // intermediate
#define NE 8      // experts

typedef __attribute__((ext_vector_type(8))) short short8;
typedef __attribute__((ext_vector_type(4))) float f32x4;

// ---------------- ws layout --------------------------------------------------
#define WS_TOP2I 0
#define WS_TOP2W 65536
#define WS_CNT   131072
#define WS_OFF   131136
#define WS_CUR   131200
#define WS_TMAP  131328
#define WS_SLOTW 196864
#define WS_ACT_OLD 524288              // old path: act bf16, 92.3 MB
// fast path:
#define WS_XB    1048576               // x bf16, 16 MB
#define WS_WGB   (WS_XB  + 16777216)
#define WS_WUB   (WS_WGB + 46137344)
#define WS_WDB   (WS_WUB + 46137344)
#define WS_ACT2  (WS_WDB + 46137344)
#define WS_NEED  ((size_t)WS_ACT2 + 92274688ULL)   // 248,512,512 B

__device__ __forceinline__ unsigned int pack_bf2(float lo, float hi) {
  unsigned int ul = __builtin_bit_cast(unsigned int, lo) + 0x8000u;
  unsigned int uh = __builtin_bit_cast(unsigned int, hi) + 0x8000u;
  return (uh & 0xffff0000u) | (ul >> 16);
}

__device__ __forceinline__ unsigned short f2bf(float f) {
  unsigned int u = __builtin_bit_cast(unsigned int, f);
  return (unsigned short)((u + 0x8000u) >> 16);
}

__device__ __forceinline__ void gload16(const void* g, void* l) {
  __builtin_amdgcn_global_load_lds(
      (const __attribute__((address_space(1))) unsigned int*)g,
      (__attribute__((address_space(3))) unsigned int*)l, 16, 0, 0);
}

// ---------------- fp32 -> bf16 bulk convert ---------------------------------
__global__ __launch_bounds__(256) void cvt_bf16_kernel(
    const float* __restrict__ in, unsigned short* __restrict__ out, int n8)
{
  int i = blockIdx.x * 256 + threadIdx.x;
  if (i >= n8) return;
  const float4* p = (const float4*)(in + (size_t)i * 8);
  float4 a = p[0], b = p[1];
  uint4 v;
  v.x = pack_bf2(a.x, a.y); v.y = pack_bf2(a.z, a.w);
  v.z = pack_bf2(b.x, b.y); v.w = pack_bf2(b.z, b.w);
  ((uint4*)out)[i] = v;
}

// ---------------- Router: fp32 logits, top-2, renormalized weights ----------
__global__ __launch_bounds__(256) void router_kernel(
    const float* __restrict__ x, const float* __restrict__ wr,
    int* __restrict__ top2i, float* __restrict__ top2w)
{
  int tid  = threadIdx.x;
  int lane = tid & 63;
  int t    = blockIdx.x * 4 + (tid >> 6);

  const float4* xp = (const float4*)(x + (size_t)t * HD + lane * 16);
  float4 xv[4];
  #pragma unroll
  for (int j = 0; j < 4; ++j) xv[j] = xp[j];

  float acc[NE];
  #pragma unroll
  for (int e = 0; e < NE; ++e) {
    const float4* wp = (const float4*)(wr + (size_t)e * HD + lane * 16);
    float s = 0.f;
    #pragma unroll
    for (int j = 0; j < 4; ++j) {
      float4 w = wp[j];
      s += xv[j].x * w.x + xv[j].y * w.y + xv[j].z * w.z + xv[j].w * w.w;
    }
    acc[e] = s;
  }
  #pragma unroll
  for (int d = 1; d < 64; d <<= 1) {
    #pragma unroll
    for (int e = 0; e < NE; ++e) acc[e] += __shfl_xor(acc[e], d, 64);
  }
  int   i0 = 0; float m0 = acc[0];
  #pragma unroll
  for (int e = 1; e < NE; ++e) if (acc[e] > m0) { m0 = acc[e]; i0 = e; }
  int   i1 = -1; float m1 = -3.4e38f;
  #pragma unroll
  for (int e = 0; e < NE; ++e) if (e != i0 && acc[e] > m1) { m1 = acc[e]; i1 = e; }

  float e1 = __expf(m1 - m0);
  float w0 = 1.f / (1.f + e1);
  float w1 = e1 * w0;

  if (lane == 0) {
    top2i[2 * t] = i0;  top2i[2 * t + 1] = i1;
    top2w[2 * t] = w0;  top2w[2 * t + 1] = w1;
  }
}

// ---------------- Count + exclusive scan (1 block) --------------------------
__global__ __launch_bounds__(256) void count_scan_kernel(
    const int* __restrict__ top2i,
    int* __restrict__ counts, int* __restrict__ offsets, int* __restrict__ cursors)
{
  __shared__ int s_cnt[NE];
  int tid = threadIdx.x;
  if (tid < NE) s_cnt[tid] = 0;
  __syncthreads();

  int c0=0,c1=0,c2=0,c3=0,c4=0,c5=0,c6=0,c7=0;
  for (int t = tid; t < TT; t += 256) {
    int e0 = top2i[2 * t], e1 = top2i[2 * t + 1];
    c0 += __popcll(__ballot(e0 == 0)) + __popcll(__ballot(e1 == 0));
    c1 += __popcll(__ballot(e0 == 1)) + __popcll(__ballot(e1 == 1));
    c2 += __popcll(__ballot(e0 == 2)) + __popcll(__ballot(e1 == 2));
    c3 += __popcll(__ballot(e0 == 3)) + __popcll(__ballot(e1 == 3));
    c4 += __popcll(__ballot(e0 == 4)) + __popcll(__ballot(e1 == 4));
    c5 += __popcll(__ballot(e0 == 5)) + __popcll(__ballot(e1 == 5));
    c6 += __popcll(__ballot(e0 == 6)) + __popcll(__ballot(e1 == 6));
    c7 += __popcll(__ballot(e0 == 7)) + __popcll(__ballot(e1 == 7));
  }
  if ((tid & 63) == 0) {
    atomicAdd(&s_cnt[0], c0); atomicAdd(&s_cnt[1], c1);
    atomicAdd(&s_cnt[2], c2); atomicAdd(&s_cnt[3], c3);
    atomicAdd(&s_cnt[4], c4); atomicAdd(&s_cnt[5], c5);
    atomicAdd(&s_cnt[6], c6); atomicAdd(&s_cnt[7], c7);
  }
  __syncthreads();
  if (tid == 0) {
    int run = 0;
    #pragma unroll
    for (int e = 0; e < NE; ++e) {
      counts[e] = s_cnt[e]; offsets[e] = run; cursors[e] = run; run += s_cnt[e];
    }
    offsets[NE] = run;
  }
}

// ---------------- Placement (wave-aggregated atomics) -----------------------
__global__ __launch_bounds__(256) void place_kernel(
    const int* __restrict__ top2i, const float* __restrict__ top2w,
    int* __restrict__ cursors,
    int* __restrict__ token_map, float* __restrict__ slot_w)
{
  int tid  = threadIdx.x;
  int lane = tid & 63;
  int t    = blockIdx.x * 256 + tid;

  #pragma unroll
  for (int k = 0; k < 2; ++k) {
    int   e = top2i[2 * t + k];
    float w = top2w[2 * t + k];
    #pragma unroll
    for (int ee = 0; ee < NE; ++ee) {
      unsigned long long m = __ballot(e == ee);
      if (e == ee) {
        int leader = __ffsll((long long)m) - 1;
        int pre    = __popcll(m & ((1ull << lane) - 1ull));
        int base   = 0;
        if (lane == leader) base = atomicAdd(&cursors[ee], (int)__popcll(m));
        base = __shfl(base, leader, 64);
        token_map[base + pre] = t;
        slot_w[base + pre]    = w;
      }
    }
  }
}

// ============================================================================
//  FAST PATH (bf16 pre-converted, m97-structure: global_load_lds w16, 128²)
// ============================================================================

// GEMM1: act[slot,i] = silu(x@wg^T) * (x@wu^T)
__global__ __launch_bounds__(256, 2) void gemm1_fast(
    const unsigned short* __restrict__ xb,
    const unsigned short* __restrict__ wgb, const unsigned short* __restrict__ wub,
    const int* __restrict__ counts, const int* __restrict__ offsets,
    const int* __restrict__ token_map, unsigned short* __restrict__ act)
{
  int e   = blockIdx.z;
  int cnt = counts[e];
  int t0  = blockIdx.x * 128;
  if (t0 >= cnt) return;
  int i0  = blockIdx.y * 128;
  int off = offsets[e];

  __shared__ unsigned short sA[128 * 64];
  __shared__ unsigned short sG[128 * 64];
  __shared__ unsigned short sU[128 * 64];

  int tid  = threadIdx.x;
  int lane = tid & 63;
  int w    = tid >> 6;
  int wr0  = (w >> 1) * 64;
  int wc0  = (w & 1) * 64;

  // staging: chunk = (w*4+j)*64 + lane; row = chunk>>3; 16B col = lane&7
  const unsigned short* asrc[4];
  const unsigned short* gsrc[4];
  const unsigned short* usrc[4];
  unsigned short* adst[4];
  unsigned short* gdst[4];
  unsigned short* udst[4];
  #pragma unroll
  for (int j = 0; j < 4; ++j) {
    int row  = (w * 4 + j) * 8 + (lane >> 3);
    int colE = (lane & 7) * 8;
    int tr   = t0 + row;
    int slot = off + (tr < cnt ? tr : cnt - 1);
    int tok  = token_map[slot];
    asrc[j] = xb  + (size_t)tok * HD + colE;
    gsrc[j] = wgb + ((size_t)e * ID + i0 + row) * HD + colE;
    usrc[j] = wub + ((size_t)e * ID + i0 + row) * HD + colE;
    adst[j] = sA + (w * 4 + j) * 512;
    gdst[j] = sG + (w * 4 + j) * 512;
    udst[j] = sU + (w * 4 + j) * 512;
  }

  f32x4 zf = {0.f, 0.f, 0.f, 0.f};
  f32x4 accg[4][4], accu[4][4];
  #pragma unroll
  for (int m = 0; m < 4; ++m)
    #pragma unroll
    for (int n = 0; n < 4; ++n) { accg[m][n] = zf; accu[m][n] = zf; }

  for (int kt = 0; kt < HD / 64; ++kt) {
    int k0 = kt * 64;
    if (kt) __syncthreads();
    #pragma unroll
    for (int j = 0; j < 4; ++j) {
      gload16(asrc[j] + k0, adst[j]);
      gload16(gsrc[j] + k0, gdst[j]);
      gload16(usrc[j] + k0, udst[j]);
    }
    __syncthreads();   // compiler emits vmcnt(0) drain here (m97 semantics)
    #pragma unroll
    for (int ks = 0; ks < 2; ++ks) {
      int kc = ks * 32 + (lane >> 4) * 8;
      short8 af[4], gf[4], uf[4];
      #pragma unroll
      for (int m = 0; m < 4; ++m)
        af[m] = *(const short8*)&sA[(wr0 + m * 16 + (lane & 15)) * 64 + kc];
      #pragma unroll
      for (int n = 0; n < 4; ++n) {
        gf[n] = *(const short8*)&sG[(wc0 + n * 16 + (lane & 15)) * 64 + kc];
        uf[n] = *(const short8*)&sU[(wc0 + n * 16 + (lane & 15)) * 64 + kc];
      }
      #pragma unroll
      for (int m = 0; m < 4; ++m)
        #pragma unroll
        for (int n = 0; n < 4; ++n) {
          accg[m][n] = __builtin_amdgcn_mfma_f32_16x16x32_bf16(af[m], gf[n], accg[m][n], 0, 0, 0);
          accu[m][n] = __builtin_amdgcn_mfma_f32_16x16x32_bf16(af[m], uf[n], accu[m][n], 0, 0, 0);
        }
    }
  }

  #pragma unroll
  for (int m = 0; m < 4; ++m) {
    #pragma unroll
    for (int r = 0; r < 4; ++r) {
      int row = wr0 + m * 16 + ((lane >> 4) << 2) + r;
      int tr2 = t0 + row;
      if (tr2 >= cnt) continue;
      size_t base = (size_t)(off + tr2) * ID + (size_t)(i0 + wc0 + (lane & 15));
      #pragma unroll
      for (int n = 0; n < 4; ++n) {
        float g = accg[m][n][r];
        float u = accu[m][n][r];
        float h = g * u / (1.f + __expf(-g));
        act[base + n * 16] = f2bf(h);
      }
    }
  }
}

// GEMM2: out[token,h] += w_slot * (act @ w_down^T)
__global__ __launch_bounds__(256, 2) void gemm2_fast(
    const unsigned short* __restrict__ act, const unsigned short* __restrict__ wdb,
    const int* __restrict__ counts, const int* __restrict__ offsets,
    const int* __restrict__ token_map, const float* __restrict__ slot_w,
    float* __restrict__ out)
{
  int e   = blockIdx.z;
  int cnt = counts[e];
  int t0  = blockIdx.x * 128;
  if (t0 >= cnt) return;
  int h0  = blockIdx.y * 128;
  int off = offsets[e];

  __shared__ unsigned short sA[128 * 64];
  __shared__ unsigned short sB[128 * 64];

  int tid  = threadIdx.x;
  int lane = tid & 63;
  int w    = tid >> 6;
  int wr0  = (w >> 1) * 64;
  int wc0  = (w & 1) * 64;

  const unsigned short* asrc[4];
  const unsigned short* bsrc[4];
  unsigned short* adst[4];
  unsigned short* bdst[4];
  #pragma unroll
  for (int j = 0; j < 4; ++j) {
    int row  = (w * 4 + j) * 8 + (lane >> 3);
    int colE = (lane & 7) * 8;
    int tr   = t0 + row;
    int slot = off + (tr < cnt ? tr : cnt - 1);
    asrc[j] = act + (size_t)slot * ID + colE;
    bsrc[j] = wdb + ((size_t)e * HD + h0 + row) * ID + colE;
    adst[j] = sA + (w * 4 + j) * 512;
    bdst[j] = sB + (w * 4 + j) * 512;
  }

  f32x4 zf = {0.f, 0.f, 0.f, 0.f};
  f32x4 acc[4][4];
  #pragma unroll
  for (int m = 0; m < 4; ++m)
    #pragma unroll
    for (int n = 0; n < 4; ++n) acc[m][n] = zf;

  for (int kt = 0; kt < ID / 64; ++kt) {
    int k0 = kt * 64;
    if (kt) __syncthreads();
    #pragma unroll
    for (int j = 0; j < 4; ++j) {
      gload16(asrc[j] + k0, adst[j]);
      gload16(bsrc[j] + k0, bdst[j]);
    }
    __syncthreads();
    #pragma unroll
    for (int ks = 0; ks < 2; ++ks) {
      int kc = ks * 32 + (lane >> 4) * 8;
      short8 af[4], bfr[4];
      #pragma unroll
      for (int m = 0; m < 4; ++m)
        af[m] = *(const short8*)&sA[(wr0 + m * 16 + (lane & 15)) * 64 + kc];
      #pragma unroll
      for (int n = 0; n < 4; ++n)
        bfr[n] = *(const short8*)&sB[(wc0 + n * 16 + (lane & 15)) * 64 + kc];
      #pragma unroll
      for (int m = 0; m < 4; ++m)
        #pragma unroll
        for (int n = 0; n < 4; ++n)
          acc[m][n] = __builtin_amdgcn_mfma_f32_16x16x32_bf16(af[m], bfr[n], acc[m][n], 0, 0, 0);
    }
  }

  #pragma unroll
  for (int m = 0; m < 4; ++m) {
    #pragma unroll
    for (int r = 0; r < 4; ++r) {
      int row = wr0 + m * 16 + ((lane >> 4) << 2) + r;
      int tr2 = t0 + row;
      if (tr2 >= cnt) continue;
      int slot = off + tr2;
      float wsl = slot_w[slot];
      float* obase = out + (size_t)token_map[slot] * HD + (size_t)(h0 + wc0 + (lane & 15));
      #pragma unroll
      for (int n = 0; n < 4; ++n)
        atomicAdd(obase + n * 16, acc[m][n][r] * wsl);
    }
  }
}

// ============================================================================
//  FALLBACK PATH (round-1 kernels, fp32 reg-staging) — used if ws too small
// ============================================================================
__device__ __forceinline__ void stage_f32(short* lds, int row, int colh, const float* src) {
  char* base = (char*)lds + row * 128;
  unsigned int swz = (unsigned int)((row & 7) << 4);
  if (src) {
    const float4* s4 = (const float4*)src;
    #pragma unroll
    for (int i = 0; i < 4; ++i) {
      float4 a = s4[2 * i], b = s4[2 * i + 1];
      uint4 v;
      v.x = pack_bf2(a.x, a.y); v.y = pack_bf2(a.z, a.w);
      v.z = pack_bf2(b.x, b.y); v.w = pack_bf2(b.z, b.w);
      *(uint4*)(base + (((unsigned int)((colh + i * 8) * 2)) ^ swz)) = v;
    }
  } else {
    uint4 z; z.x = z.y = z.z = z.w = 0u;
    #pragma unroll
    for (int i = 0; i < 4; ++i)
      *(uint4*)(base + (((unsigned int)((colh + i * 8) * 2)) ^ swz)) = z;
  }
}

__device__ __forceinline__ void stage_bf16s(short* lds, int row, int colh, const unsigned short* src) {
  char* base = (char*)lds + row * 128;
  unsigned int swz = (unsigned int)((row & 7) << 4);
  if (src) {
    const uint4* s4 = (const uint4*)src;
    #pragma unroll
    for (int i = 0; i < 4; ++i)
      *(uint4*)(base + (((unsigned int)((colh + i * 8) * 2)) ^ swz)) = s4[i];
  } else {
    uint4 z; z.x = z.y = z.z = z.w = 0u;
    #pragma unroll
    for (int i = 0; i < 4; ++i)
      *(uint4*)(base + (((unsigned int)((colh + i * 8) * 2)) ^ swz)) = z;
  }
}

__device__ __forceinline__ short8 ldfrag(const short* lds, int row, int kc) {
  unsigned int off = (unsigned int)(row * 128) +
                     (((unsigned int)(kc * 2)) ^ ((unsigned int)((row & 7) << 4)));
  return *(const short8*)((const char*)lds + off);
}

__global__ __launch_bounds__(256, 2) void gemm1_kernel(
    const float* __restrict__ x,
    const float* __restrict__ w_gate, const float* __restrict__ w_up,
    const int* __restrict__ counts, const int* __restrict__ offsets,
    const int* __restrict__ token_map, unsigned short* __restrict__ act)
{
  int e   = blockIdx.z;
  int cnt = counts[e];
  int t0  = blockIdx.x * 128;
  if (t0 >= cnt) return;
  int i0  = blockIdx.y * 128;
  int off = offsets[e];

  __shared__ short sA[128 * 64];
  __shared__ short sG[128 * 64];
  __shared__ short sU[128 * 64];

  int tid  = threadIdx.x;
  int lane = tid & 63;
  int wid  = tid >> 6;
  int wr0  = (wid >> 1) * 64;
  int wc0  = (wid & 1) * 64;

  int srow = tid >> 1;
  int colh = (tid & 1) * 32;

  const float* aptr = nullptr;
  int tr = t0 + srow;
  if (tr < cnt) aptr = x + (size_t)token_map[off + tr] * HD + colh;
  const float* gptr = w_gate + (size_t)e * ID * HD + (size_t)(i0 + srow) * HD + colh;
  const float* uptr = w_up   + (size_t)e * ID * HD + (size_t)(i0 + srow) * HD + colh;

  f32x4 zf = {0.f, 0.f, 0.f, 0.f};
  f32x4 accg[4][4], accu[4][4];
  #pragma unroll
  for (int m = 0; m < 4; ++m)
    #pragma unroll
    for (int n = 0; n < 4; ++n) { accg[m][n] = zf; accu[m][n] = zf; }

  for (int kt = 0; kt < HD / 64; ++kt) {
    int k0 = kt * 64;
    if (kt) __syncthreads();
    stage_f32(sA, srow, colh, aptr ? aptr + k0 : nullptr);
    stage_f32(sG, srow, colh, gptr + k0);
    stage_f32(sU, srow, colh, uptr + k0);
    __syncthreads();
    #pragma unroll
    for (int ks = 0; ks < 2; ++ks) {
      int kc = ks * 32 + (lane >> 4) * 8;
      short8 af[4], gf[4], uf[4];
      #pragma unroll
      for (int m = 0; m < 4; ++m) af[m] = ldfrag(sA, wr0 + m * 16 + (lane & 15), kc);
      #pragma unroll
      for (int n = 0; n < 4; ++n) {
        gf[n] = ldfrag(sG, wc0 + n * 16 + (lane & 15), kc);
        uf[n] = ldfrag(sU, wc0 + n * 16 + (lane & 15), kc);
      }
      #pragma unroll
      for (int m = 0; m < 4; ++m)
        #pragma unroll
        for (int n = 0; n < 4; ++n) {
          accg[m][n] = __builtin_amdgcn_mfma_f32_16x16x32_bf16(af[m], gf[n], accg[m][n], 0, 0, 0);
          accu[m][n] = __builtin_amdgcn_mfma_f32_16x16x32_bf16(af[m], uf[n], accu[m][n], 0, 0, 0);
        }
    }
  }

  #pragma unroll
  for (int m = 0; m < 4; ++m) {
    #pragma unroll
    for (int r = 0; r < 4; ++r) {
      int row = wr0 + m * 16 + ((lane >> 4) << 2) + r;
      int tr2 = t0 + row;
      if (tr2 >= cnt) continue;
      size_t base = (size_t)(off + tr2) * ID + (size_t)(i0 + wc0 + (lane & 15));
      #pragma unroll
      for (int n = 0; n < 4; ++n) {
        float g = accg[m][n][r];
        float u = accu[m][n][r];
        float h = g * u / (1.f + __expf(-g));
        act[base + n * 16] = f2bf(h);
      }
    }
  }
}

__global__ __launch_bounds__(256, 2) void gemm2_kernel(
    const unsigned short* __restrict__ act, const float* __restrict__ w_down,
    const int* __restrict__ counts, const int* __restrict__ offsets,
    const int* __restrict__ token_map, const float* __restrict__ slot_w,
    float* __restrict__ out)
{
  int e   = blockIdx.z;
  int cnt = counts[e];
  int t0  = blockIdx.x * 128;
  if (t0 >= cnt) return;
  int h0  = blockIdx.y * 128;
  int off = offsets[e];

  __shared__ short sA[128 * 64];
  __shared__ short sB[128 * 64];

  int tid  = threadIdx.x;
  int lane = tid & 63;
  int wid  = tid >> 6;
  int wr0  = (wid >> 1) * 64;
  int wc0  = (wid & 1) * 64;

  int srow = tid >> 1;
  int colh = (tid & 1) * 32;

  const unsigned short* aptr = nullptr;
  int tr = t0 + srow;
  if (tr < cnt) aptr = act + (size_t)(off + tr) * ID + colh;
  const float* bptr = w_down + (size_t)e * HD * ID + (size_t)(h0 + srow) * ID + colh;

  f32x4 zf = {0.f, 0.f, 0.f, 0.f};
  f32x4 acc[4][4];
  #pragma unroll
  for (int m = 0; m < 4; ++m)
    #pragma unroll
    for (int n = 0; n < 4; ++n) acc[m][n] = zf;

  for (int kt = 0; kt < ID / 64; ++kt) {
    int k0 = kt * 64;
    if (kt) __syncthreads();
    stage_bf16s(sA, srow, colh, aptr ? aptr + k0 : nullptr);
    stage_f32(sB, srow, colh, bptr + k0);
    __syncthreads();
    #pragma unroll
    for (int ks = 0; ks < 2; ++ks) {
      int kc = ks * 32 + (lane >> 4) * 8;
      short8 af[4], bfr[4];
      #pragma unroll
      for (int m = 0; m < 4; ++m) af[m] = ldfrag(sA, wr0 + m * 16 + (lane & 15), kc);
      #pragma unroll
      for (int n = 0; n < 4; ++n) bfr[n] = ldfrag(sB, wc0 + n * 16 + (lane & 15), kc);
      #pragma unroll
      for (int m = 0; m < 4; ++m)
        #pragma unroll
        for (int n = 0; n < 4; ++n)
          acc[m][n] = __builtin_amdgcn_mfma_f32_16x16x32_bf16(af[m], bfr[n], acc[m][n], 0, 0, 0);
    }
  }

  #pragma unroll
  for (int m = 0; m < 4; ++m) {
    #pragma unroll
    for (int r = 0; r < 4; ++r) {
      int row = wr0 + m * 16 + ((lane >> 4) << 2) + r;
      int tr2 = t0 + row;
      if (tr2 >= cnt) continue;
      int slot = off + tr2;
      float wv = slot_w[slot];
      float* obase = out + (size_t)token_map[slot] * HD + (size_t)(h0 + wc0 + (lane & 15));
      #pragma unroll
      for (int n = 0; n < 4; ++n)
        atomicAdd(obase + n * 16, acc[m][n][r] * wv);
    }
  }
}

// ---------------- launch ----------------------------------------------------
extern "C" void kernel_launch(void* const* d_in, const int* in_sizes, int n_in,
                              void* d_out, int out_size, void* d_ws, size_t ws_size,
                              hipStream_t stream) {
  const float* x        = (const float*)d_in[0];
  const float* w_router = (const float*)d_in[1];
  const float* w_gate   = (const float*)d_in[2];
  const float* w_up     = (const float*)d_in[3];
  const float* w_down   = (const float*)d_in[4];

  char* ws = (char*)d_ws;
  int*   top2i   = (int*)(ws + WS_TOP2I);
  float* top2w   = (float*)(ws + WS_TOP2W);
  int*   counts  = (int*)(ws + WS_CNT);
  int*   offsets = (int*)(ws + WS_OFF);
  int*   cursors = (int*)(ws + WS_CUR);
  int*   tmap    = (int*)(ws + WS_TMAP);
  float* slotw   = (float*)(ws + WS_SLOTW);

  hipMemsetAsync(d_out, 0, (size_t)out_size * sizeof(float), stream);
  router_kernel<<<TT / 4, 256, 0, stream>>>(x, w_router, top2i, top2w);
  count_scan_kernel<<<1, 256, 0, stream>>>(top2i, counts, offsets, cursors);
  place_kernel<<<TT / 256, 256, 0, stream>>>(top2i, top2w, cursors, tmap, slotw);

  if (ws_size >= WS_NEED) {
    unsigned short* xb  = (unsigned short*)(ws + WS_XB);
    unsigned short* wgb = (unsigned short*)(ws + WS_WGB);
    unsigned short* wub = (unsigned short*)(ws + WS_WUB);
    unsigned short* wdb = (unsigned short*)(ws + WS_WDB);
    unsigned short* act = (unsigned short*)(ws + WS_ACT2);

    cvt_bf16_kernel<<<4096, 256, 0, stream>>>(x, xb, TT * HD / 8);
    cvt_bf16_kernel<<<11264, 256, 0, stream>>>(w_gate, wgb, NE * ID * HD / 8);
    cvt_bf16_kernel<<<11264, 256, 0, stream>>>(w_up,   wub, NE * ID * HD / 8);
    cvt_bf16_kernel<<<11264, 256, 0, stream>>>(w_down, wdb, NE * HD * ID / 8);

    gemm1_fast<<<dim3(64, 22, NE), 256, 0, stream>>>(xb, wgb, wub, counts, offsets, tmap, act);
    gemm2_fast<<<dim3(64, 8, NE), 256, 0, stream>>>(act, wdb, counts, offsets, tmap, slotw, (float*)d_out);
  } else {
    unsigned short* act = (unsigned short*)(ws + WS_ACT_OLD);
    gemm1_kernel<<<dim3(64, 22, NE), 256, 0, stream>>>(x, w_gate, w_up, counts, offsets, tmap, act);
    gemm2_kernel<<<dim3(64, 8, NE), 256, 0, stream>>>(act, w_down, counts, offsets, tmap, slotw, (float*)d_out);
  }
}

// Round 3
// 824.907 us; speedup vs baseline: 1.9855x; 1.0881x over previous
//
#include <hip/hip_runtime.h>

#define TT 8192   // tokens
#define HD 1024   // hidden
#define ID 2816   // intermediate
#define NE 8      // experts
#define NID2 (2*ID)   // 5632 interleaved gate/up rows per expert

typedef __attribute__((ext_vector_type(8))) short short8;
typedef __attribute__((ext_vector_type(4))) float f32x4;

// ---------------- ws layout --------------------------------------------------
#define WS_TOP2I 0
#define WS_TOP2W 65536
#define WS_CNT   131072
#define WS_OFF   131136
#define WS_CUR   131200
#define WS_TMAP  131328
#define WS_SLOTW 196864
#define WS_XB    1048576ULL                  // x bf16, 16 MB
#define WS_WGU   (WS_XB  + 16777216ULL)      // interleaved gate/up bf16, 92.3 MB
#define WS_WDB   (WS_WGU + 92274688ULL)      // w_down bf16, 46.1 MB
#define WS_ACT   (WS_WDB + 46137344ULL)      // act bf16, 92.3 MB
#define WS_NEED  (WS_ACT + 92274688ULL)      // 248,512,512 B (same as R2's, known to fit)

__device__ __forceinline__ unsigned int pack_bf2(float lo, float hi) {
  unsigned int ul = __builtin_bit_cast(unsigned int, lo) + 0x8000u;
  unsigned int uh = __builtin_bit_cast(unsigned int, hi) + 0x8000u;
  return (uh & 0xffff0000u) | (ul >> 16);
}

__device__ __forceinline__ unsigned short f2bf(float f) {
  unsigned int u = __builtin_bit_cast(unsigned int, f);
  return (unsigned short)((u + 0x8000u) >> 16);
}

__device__ __forceinline__ void gload16(const void* g, void* l) {
  __builtin_amdgcn_global_load_lds(
      (const __attribute__((address_space(1))) unsigned int*)g,
      (__attribute__((address_space(3))) unsigned int*)l, 16, 0, 0);
}

// ---------------- Router: fp32 logits, top-2; also emits x as bf16 ----------
__global__ __launch_bounds__(256) void router_kernel(
    const float* __restrict__ x, const float* __restrict__ wr,
    int* __restrict__ top2i, float* __restrict__ top2w,
    unsigned short* __restrict__ xb)
{
  int tid  = threadIdx.x;
  int lane = tid & 63;
  int t    = blockIdx.x * 4 + (tid >> 6);

  const float4* xp = (const float4*)(x + (size_t)t * HD + lane * 16);
  float4 xv[4];
  #pragma unroll
  for (int j = 0; j < 4; ++j) xv[j] = xp[j];

  // write bf16 copy of x (saves a separate conversion pass)
  uint4 v0, v1;
  v0.x = pack_bf2(xv[0].x, xv[0].y); v0.y = pack_bf2(xv[0].z, xv[0].w);
  v0.z = pack_bf2(xv[1].x, xv[1].y); v0.w = pack_bf2(xv[1].z, xv[1].w);
  v1.x = pack_bf2(xv[2].x, xv[2].y); v1.y = pack_bf2(xv[2].z, xv[2].w);
  v1.z = pack_bf2(xv[3].x, xv[3].y); v1.w = pack_bf2(xv[3].z, xv[3].w);
  uint4* xrow = (uint4*)(xb + (size_t)t * HD + lane * 16);
  xrow[0] = v0; xrow[1] = v1;

  float acc[NE];
  #pragma unroll
  for (int e = 0; e < NE; ++e) {
    const float4* wp = (const float4*)(wr + (size_t)e * HD + lane * 16);
    float s = 0.f;
    #pragma unroll
    for (int j = 0; j < 4; ++j) {
      float4 w = wp[j];
      s += xv[j].x * w.x + xv[j].y * w.y + xv[j].z * w.z + xv[j].w * w.w;
    }
    acc[e] = s;
  }
  #pragma unroll
  for (int d = 1; d < 64; d <<= 1) {
    #pragma unroll
    for (int e = 0; e < NE; ++e) acc[e] += __shfl_xor(acc[e], d, 64);
  }
  int   i0 = 0; float m0 = acc[0];
  #pragma unroll
  for (int e = 1; e < NE; ++e) if (acc[e] > m0) { m0 = acc[e]; i0 = e; }
  int   i1 = -1; float m1 = -3.4e38f;
  #pragma unroll
  for (int e = 0; e < NE; ++e) if (e != i0 && acc[e] > m1) { m1 = acc[e]; i1 = e; }

  float e1 = __expf(m1 - m0);
  float w0 = 1.f / (1.f + e1);
  float w1 = e1 * w0;

  if (lane == 0) {
    top2i[2 * t] = i0;  top2i[2 * t + 1] = i1;
    top2w[2 * t] = w0;  top2w[2 * t + 1] = w1;
  }
}

// ---------------- Count + exclusive scan (1 block) --------------------------
__global__ __launch_bounds__(256) void count_scan_kernel(
    const int* __restrict__ top2i,
    int* __restrict__ counts, int* __restrict__ offsets, int* __restrict__ cursors)
{
  __shared__ int s_cnt[NE];
  int tid = threadIdx.x;
  if (tid < NE) s_cnt[tid] = 0;
  __syncthreads();

  int c0=0,c1=0,c2=0,c3=0,c4=0,c5=0,c6=0,c7=0;
  for (int t = tid; t < TT; t += 256) {
    int e0 = top2i[2 * t], e1 = top2i[2 * t + 1];
    c0 += __popcll(__ballot(e0 == 0)) + __popcll(__ballot(e1 == 0));
    c1 += __popcll(__ballot(e0 == 1)) + __popcll(__ballot(e1 == 1));
    c2 += __popcll(__ballot(e0 == 2)) + __popcll(__ballot(e1 == 2));
    c3 += __popcll(__ballot(e0 == 3)) + __popcll(__ballot(e1 == 3));
    c4 += __popcll(__ballot(e0 == 4)) + __popcll(__ballot(e1 == 4));
    c5 += __popcll(__ballot(e0 == 5)) + __popcll(__ballot(e1 == 5));
    c6 += __popcll(__ballot(e0 == 6)) + __popcll(__ballot(e1 == 6));
    c7 += __popcll(__ballot(e0 == 7)) + __popcll(__ballot(e1 == 7));
  }
  if ((tid & 63) == 0) {
    atomicAdd(&s_cnt[0], c0); atomicAdd(&s_cnt[1], c1);
    atomicAdd(&s_cnt[2], c2); atomicAdd(&s_cnt[3], c3);
    atomicAdd(&s_cnt[4], c4); atomicAdd(&s_cnt[5], c5);
    atomicAdd(&s_cnt[6], c6); atomicAdd(&s_cnt[7], c7);
  }
  __syncthreads();
  if (tid == 0) {
    int run = 0;
    #pragma unroll
    for (int e = 0; e < NE; ++e) {
      counts[e] = s_cnt[e]; offsets[e] = run; cursors[e] = run; run += s_cnt[e];
    }
    offsets[NE] = run;
  }
}

// ---------------- Placement (wave-aggregated atomics) -----------------------
__global__ __launch_bounds__(256) void place_kernel(
    const int* __restrict__ top2i, const float* __restrict__ top2w,
    int* __restrict__ cursors,
    int* __restrict__ token_map, float* __restrict__ slot_w)
{
  int tid  = threadIdx.x;
  int lane = tid & 63;
  int t    = blockIdx.x * 256 + tid;

  #pragma unroll
  for (int k = 0; k < 2; ++k) {
    int   e = top2i[2 * t + k];
    float w = top2w[2 * t + k];
    #pragma unroll
    for (int ee = 0; ee < NE; ++ee) {
      unsigned long long m = __ballot(e == ee);
      if (e == ee) {
        int leader = __ffsll((long long)m) - 1;
        int pre    = __popcll(m & ((1ull << lane) - 1ull));
        int base   = 0;
        if (lane == leader) base = atomicAdd(&cursors[ee], (int)__popcll(m));
        base = __shfl(base, leader, 64);
        token_map[base + pre] = t;
        slot_w[base + pre]    = w;
      }
    }
  }
}

// ---------------- weight converts -------------------------------------------
// Interleaved gate/up: per expert, per i-block of 128: 128 gate rows then 128 up rows
__global__ __launch_bounds__(256) void cvt_wgu_kernel(
    const float* __restrict__ wg, const float* __restrict__ wu,
    unsigned short* __restrict__ wgu)
{
  int e   = blockIdx.y;
  int idx = blockIdx.x * 256 + threadIdx.x;    // chunk of 8 elems within expert
  int col8 = idx & 127;                        // 1024/8
  int rr   = idx >> 7;                         // 0..5631 interleaved row
  int blk  = rr >> 8;
  int win  = rr & 255;
  const float* srow = (win < 128)
      ? wg + ((size_t)e * ID + blk * 128 + win) * HD
      : wu + ((size_t)e * ID + blk * 128 + (win - 128)) * HD;
  const float4* p = (const float4*)(srow + col8 * 8);
  float4 a = p[0], b = p[1];
  uint4 v;
  v.x = pack_bf2(a.x, a.y); v.y = pack_bf2(a.z, a.w);
  v.z = pack_bf2(b.x, b.y); v.w = pack_bf2(b.z, b.w);
  *(uint4*)(wgu + ((size_t)e * NID2 + rr) * HD + col8 * 8) = v;
}

__global__ __launch_bounds__(256) void cvt_bf16_kernel(
    const float* __restrict__ in, unsigned short* __restrict__ out, int n8)
{
  int i = blockIdx.x * 256 + threadIdx.x;
  if (i >= n8) return;
  const float4* p = (const float4*)(in + (size_t)i * 8);
  float4 a = p[0], b = p[1];
  uint4 v;
  v.x = pack_bf2(a.x, a.y); v.y = pack_bf2(a.z, a.w);
  v.z = pack_bf2(b.x, b.y); v.w = pack_bf2(b.z, b.w);
  ((uint4*)out)[i] = v;
}

// ============================================================================
//  GEMM core: BM=128 x BN=256 x BK=64, 8 waves, 3-slot LDS ring, counted vmcnt
//  LDS slot = A[128][64] (16KB) + B[256][64] (32KB) = 48KB; 3 slots = 144KB
//  T2 swizzle: source col8 = (l&7)^(2*(l>>5)); read byte ^= ((lane>>2)&1)<<5
// ============================================================================

// GEMM1: gate/up interleaved B; epilogue exchanges up-acc via LDS, fuses silu
__global__ __launch_bounds__(512, 2) void gemm1_fast(
    const unsigned short* __restrict__ xb, const unsigned short* __restrict__ wgu,
    const int* __restrict__ counts, const int* __restrict__ offsets,
    const int* __restrict__ token_map, unsigned short* __restrict__ act)
{
  extern __shared__ char smem[];               // 147456 B
  unsigned short* lds = (unsigned short*)smem;

  int e   = blockIdx.z;
  int cnt = counts[e];
  int t0  = blockIdx.x * 128;
  if (t0 >= cnt) return;
  int y   = blockIdx.y;                        // i-block 0..21
  int off = offsets[e];

  int tid  = threadIdx.x;
  int lane = tid & 63;
  int w    = tid >> 6;
  int wr   = w >> 2;                           // 0..1  (row half)
  int wc   = w & 3;                            // 0..3  (col quarter; 0,1=gate 2,3=up)

  // staging: wave w owns A-chunks {2w,2w+1}, B-chunks {4w..4w+3} (1024B each)
  int lr   = lane >> 3;
  int colE = (((lane & 7) ^ ((lane >> 5) << 1)) << 3);   // pre-swizzled source col
  const unsigned short* asrc[2];
  const unsigned short* bsrc[4];
  unsigned int adst[2], bdst[4];
  #pragma unroll
  for (int j = 0; j < 2; ++j) {
    int c   = 2 * w + j;
    int row = c * 8 + lr;
    int tr  = t0 + row;
    int slot = off + (tr < cnt ? tr : cnt - 1);
    asrc[j] = xb + (size_t)token_map[slot] * HD + colE;
    adst[j] = c * 512;
  }
  #pragma unroll
  for (int j = 0; j < 4; ++j) {
    int c   = 4 * w + j;
    int row = c * 8 + lr;
    bsrc[j] = wgu + ((size_t)e * NID2 + (size_t)y * 256 + row) * HD + colE;
    bdst[j] = 8192 + c * 512;
  }

  f32x4 zf = {0.f, 0.f, 0.f, 0.f};
  f32x4 acc[4][4];
  #pragma unroll
  for (int m = 0; m < 4; ++m)
    #pragma unroll
    for (int n = 0; n < 4; ++n) acc[m][n] = zf;

  const int nkt = HD / 64;                     // 16
  int swzx = ((lane >> 2) & 1) << 5;           // read-side byte xor
  int arow = lane & 15;
  int kq   = (lane >> 4) << 4;                 // byte offset of k-quarter

  #define STAGE1(t) { \
    int k0 = (t) * 64; \
    unsigned short* sb = lds + ((t) % 3) * 24576; \
    _Pragma("unroll") for (int j = 0; j < 2; ++j) gload16(asrc[j] + k0, sb + adst[j]); \
    _Pragma("unroll") for (int j = 0; j < 4; ++j) gload16(bsrc[j] + k0, sb + bdst[j]); }

  #define COMPUTE1(t) { \
    const char* sa = (const char*)(lds + ((t) % 3) * 24576); \
    const char* sB = sa + 16384; \
    _Pragma("unroll") for (int kk = 0; kk < 2; ++kk) { \
      int kb = kk * 64 + kq; \
      short8 af[4], bfr[4]; \
      _Pragma("unroll") for (int m = 0; m < 4; ++m) \
        af[m] = *(const short8*)(sa + (wr * 64 + m * 16 + arow) * 128 + (kb ^ swzx)); \
      _Pragma("unroll") for (int n = 0; n < 4; ++n) \
        bfr[n] = *(const short8*)(sB + (wc * 64 + n * 16 + arow) * 128 + (kb ^ swzx)); \
      _Pragma("unroll") for (int m = 0; m < 4; ++m) \
        _Pragma("unroll") for (int n = 0; n < 4; ++n) \
          acc[m][n] = __builtin_amdgcn_mfma_f32_16x16x32_bf16(af[m], bfr[n], acc[m][n], 0, 0, 0); } }

  STAGE1(0); STAGE1(1);
  asm volatile("s_waitcnt vmcnt(6)" ::: "memory");
  __builtin_amdgcn_s_barrier();
  for (int t = 0; t < nkt - 2; ++t) {
    STAGE1(t + 2);
    COMPUTE1(t);
    asm volatile("s_waitcnt vmcnt(6)" ::: "memory");
    __builtin_amdgcn_s_barrier();
  }
  COMPUTE1(nkt - 2);
  asm volatile("s_waitcnt vmcnt(0)" ::: "memory");
  __builtin_amdgcn_s_barrier();
  COMPUTE1(nkt - 1);

  // ---- epilogue: up-waves publish acc; gate-waves fuse silu(g)*u ----
  __syncthreads();
  float* xch = (float*)smem;
  int prow = (lane >> 4) << 2;
  int pcol = lane & 15;
  if (wc >= 2) {
    float* base = xch + (size_t)((wr * 2 + (wc - 2)) * 4096);
    #pragma unroll
    for (int m = 0; m < 4; ++m)
      #pragma unroll
      for (int n = 0; n < 4; ++n)
        #pragma unroll
        for (int r = 0; r < 4; ++r)
          base[(m * 16 + prow + r) * 64 + n * 16 + pcol] = acc[m][n][r];
  }
  __syncthreads();
  if (wc < 2) {
    const float* base = xch + (size_t)((wr * 2 + wc) * 4096);
    int i0 = y * 128 + wc * 64;
    #pragma unroll
    for (int m = 0; m < 4; ++m) {
      #pragma unroll
      for (int r = 0; r < 4; ++r) {
        int row = wr * 64 + m * 16 + prow + r;
        int tr2 = t0 + row;
        if (tr2 >= cnt) continue;
        size_t obase = (size_t)(off + tr2) * ID + i0 + pcol;
        #pragma unroll
        for (int n = 0; n < 4; ++n) {
          float g = acc[m][n][r];
          float u = base[(m * 16 + prow + r) * 64 + n * 16 + pcol];
          float h = g * u / (1.f + __expf(-g));
          act[obase + n * 16] = f2bf(h);
        }
      }
    }
  }
}

// GEMM2: out[token,h] += w_slot * (act @ w_down^T)
__global__ __launch_bounds__(512, 2) void gemm2_fast(
    const unsigned short* __restrict__ act, const unsigned short* __restrict__ wdb,
    const int* __restrict__ counts, const int* __restrict__ offsets,
    const int* __restrict__ token_map, const float* __restrict__ slot_w,
    float* __restrict__ out)
{
  extern __shared__ char smem[];
  unsigned short* lds = (unsigned short*)smem;

  int e   = blockIdx.z;
  int cnt = counts[e];
  int t0  = blockIdx.x * 128;
  if (t0 >= cnt) return;
  int y   = blockIdx.y;                        // h-block 0..3 (256 cols each)
  int off = offsets[e];

  int tid  = threadIdx.x;
  int lane = tid & 63;
  int w    = tid >> 6;
  int wr   = w >> 2;
  int wc   = w & 3;

  int lr   = lane >> 3;
  int colE = (((lane & 7) ^ ((lane >> 5) << 1)) << 3);
  const unsigned short* asrc[2];
  const unsigned short* bsrc[4];
  unsigned int adst[2], bdst[4];
  #pragma unroll
  for (int j = 0; j < 2; ++j) {
    int c   = 2 * w + j;
    int row = c * 8 + lr;
    int tr  = t0 + row;
    int slot = off + (tr < cnt ? tr : cnt - 1);
    asrc[j] = act + (size_t)slot * ID + colE;
    adst[j] = c * 512;
  }
  #pragma unroll
  for (int j = 0; j < 4; ++j) {
    int c   = 4 * w + j;
    int row = c * 8 + lr;
    bsrc[j] = wdb + ((size_t)e * HD + (size_t)y * 256 + row) * ID + colE;
    bdst[j] = 8192 + c * 512;
  }

  f32x4 zf = {0.f, 0.f, 0.f, 0.f};
  f32x4 acc[4][4];
  #pragma unroll
  for (int m = 0; m < 4; ++m)
    #pragma unroll
    for (int n = 0; n < 4; ++n) acc[m][n] = zf;

  const int nkt = ID / 64;                     // 44
  int swzx = ((lane >> 2) & 1) << 5;
  int arow = lane & 15;
  int kq   = (lane >> 4) << 4;

  STAGE1(0); STAGE1(1);
  asm volatile("s_waitcnt vmcnt(6)" ::: "memory");
  __builtin_amdgcn_s_barrier();
  for (int t = 0; t < nkt - 2; ++t) {
    STAGE1(t + 2);
    COMPUTE1(t);
    asm volatile("s_waitcnt vmcnt(6)" ::: "memory");
    __builtin_amdgcn_s_barrier();
  }
  COMPUTE1(nkt - 2);
  asm volatile("s_waitcnt vmcnt(0)" ::: "memory");
  __builtin_amdgcn_s_barrier();
  COMPUTE1(nkt - 1);

  int prow = (lane >> 4) << 2;
  int pcol = lane & 15;
  #pragma unroll
  for (int m = 0; m < 4; ++m) {
    #pragma unroll
    for (int r = 0; r < 4; ++r) {
      int row = wr * 64 + m * 16 + prow + r;
      int tr2 = t0 + row;
      if (tr2 >= cnt) continue;
      int slot = off + tr2;
      float wsl = slot_w[slot];
      float* ob = out + (size_t)token_map[slot] * HD + y * 256 + wc * 64 + pcol;
      #pragma unroll
      for (int n = 0; n < 4; ++n)
        atomicAdd(ob + n * 16, acc[m][n][r] * wsl);
    }
  }
}

// ---------------- launch ----------------------------------------------------
extern "C" void kernel_launch(void* const* d_in, const int* in_sizes, int n_in,
                              void* d_out, int out_size, void* d_ws, size_t ws_size,
                              hipStream_t stream) {
  const float* x        = (const float*)d_in[0];
  const float* w_router = (const float*)d_in[1];
  const float* w_gate   = (const float*)d_in[2];
  const float* w_up     = (const float*)d_in[3];
  const float* w_down   = (const float*)d_in[4];

  char* ws = (char*)d_ws;
  int*   top2i   = (int*)(ws + WS_TOP2I);
  float* top2w   = (float*)(ws + WS_TOP2W);
  int*   counts  = (int*)(ws + WS_CNT);
  int*   offsets = (int*)(ws + WS_OFF);
  int*   cursors = (int*)(ws + WS_CUR);
  int*   tmap    = (int*)(ws + WS_TMAP);
  float* slotw   = (float*)(ws + WS_SLOTW);
  unsigned short* xb  = (unsigned short*)(ws + WS_XB);
  unsigned short* wgu = (unsigned short*)(ws + WS_WGU);
  unsigned short* wdb = (unsigned short*)(ws + WS_WDB);
  unsigned short* act = (unsigned short*)(ws + WS_ACT);

  hipFuncSetAttribute((const void*)gemm1_fast,
                      hipFuncAttributeMaxDynamicSharedMemorySize, 147456);
  hipFuncSetAttribute((const void*)gemm2_fast,
                      hipFuncAttributeMaxDynamicSharedMemorySize, 147456);

  hipMemsetAsync(d_out, 0, (size_t)out_size * sizeof(float), stream);
  router_kernel<<<TT / 4, 256, 0, stream>>>(x, w_router, top2i, top2w, xb);
  count_scan_kernel<<<1, 256, 0, stream>>>(top2i, counts, offsets, cursors);
  place_kernel<<<TT / 256, 256, 0, stream>>>(top2i, top2w, cursors, tmap, slotw);
  cvt_wgu_kernel<<<dim3(2816, NE), 256, 0, stream>>>(w_gate, w_up, wgu);
  cvt_bf16_kernel<<<11264, 256, 0, stream>>>(w_down, wdb, NE * HD * ID / 8);

  gemm1_fast<<<dim3(64, 22, NE), 512, 147456, stream>>>(xb, wgu, counts, offsets, tmap, act);
  gemm2_fast<<<dim3(64, 4, NE), 512, 147456, stream>>>(act, wdb, counts, offsets, tmap, slotw, (float*)d_out);
}

// Round 4
// 800.400 us; speedup vs baseline: 2.0463x; 1.0306x over previous
//
#include <hip/hip_runtime.h>

#define TT 8192   // tokens
#define HD 1024   // hidden
#define ID 2816   // intermediate
#define NE 8      // experts
#define NID2 (2*ID)   // 5632 interleaved gate/up rows per expert

typedef __attribute__((ext_vector_type(8))) short short8;
typedef __attribute__((ext_vector_type(4))) float f32x4;

// ---------------- ws layout --------------------------------------------------
#define WS_TOP2I 0
#define WS_TOP2W 65536
#define WS_CNT   131072
#define WS_OFF   131136
#define WS_CUR   131200
#define WS_TMAP  131328
#define WS_SLOTW 196864
#define WS_XB    1048576ULL                  // x bf16, 16 MB
#define WS_WGU   (WS_XB  + 16777216ULL)      // interleaved gate/up bf16, 92.3 MB
#define WS_WDB   (WS_WGU + 92274688ULL)      // w_down bf16, 46.1 MB
#define WS_ACT   (WS_WDB + 46137344ULL)      // act bf16, 92.3 MB

__device__ __forceinline__ unsigned int pack_bf2(float lo, float hi) {
  unsigned int ul = __builtin_bit_cast(unsigned int, lo) + 0x8000u;
  unsigned int uh = __builtin_bit_cast(unsigned int, hi) + 0x8000u;
  return (uh & 0xffff0000u) | (ul >> 16);
}

__device__ __forceinline__ unsigned short f2bf(float f) {
  unsigned int u = __builtin_bit_cast(unsigned int, f);
  return (unsigned short)((u + 0x8000u) >> 16);
}

__device__ __forceinline__ void gload16(const void* g, void* l) {
  __builtin_amdgcn_global_load_lds(
      (const __attribute__((address_space(1))) unsigned int*)g,
      (__attribute__((address_space(3))) unsigned int*)l, 16, 0, 0);
}

// ---------------- Router: fp32 logits, top-2; also emits x as bf16 ----------
__global__ __launch_bounds__(256) void router_kernel(
    const float* __restrict__ x, const float* __restrict__ wr,
    int* __restrict__ top2i, float* __restrict__ top2w,
    unsigned short* __restrict__ xb)
{
  int tid  = threadIdx.x;
  int lane = tid & 63;
  int t    = blockIdx.x * 4 + (tid >> 6);

  const float4* xp = (const float4*)(x + (size_t)t * HD + lane * 16);
  float4 xv[4];
  #pragma unroll
  for (int j = 0; j < 4; ++j) xv[j] = xp[j];

  uint4 v0, v1;
  v0.x = pack_bf2(xv[0].x, xv[0].y); v0.y = pack_bf2(xv[0].z, xv[0].w);
  v0.z = pack_bf2(xv[1].x, xv[1].y); v0.w = pack_bf2(xv[1].z, xv[1].w);
  v1.x = pack_bf2(xv[2].x, xv[2].y); v1.y = pack_bf2(xv[2].z, xv[2].w);
  v1.z = pack_bf2(xv[3].x, xv[3].y); v1.w = pack_bf2(xv[3].z, xv[3].w);
  uint4* xrow = (uint4*)(xb + (size_t)t * HD + lane * 16);
  xrow[0] = v0; xrow[1] = v1;

  float acc[NE];
  #pragma unroll
  for (int e = 0; e < NE; ++e) {
    const float4* wp = (const float4*)(wr + (size_t)e * HD + lane * 16);
    float s = 0.f;
    #pragma unroll
    for (int j = 0; j < 4; ++j) {
      float4 w = wp[j];
      s += xv[j].x * w.x + xv[j].y * w.y + xv[j].z * w.z + xv[j].w * w.w;
    }
    acc[e] = s;
  }
  #pragma unroll
  for (int d = 1; d < 64; d <<= 1) {
    #pragma unroll
    for (int e = 0; e < NE; ++e) acc[e] += __shfl_xor(acc[e], d, 64);
  }
  int   i0 = 0; float m0 = acc[0];
  #pragma unroll
  for (int e = 1; e < NE; ++e) if (acc[e] > m0) { m0 = acc[e]; i0 = e; }
  int   i1 = -1; float m1 = -3.4e38f;
  #pragma unroll
  for (int e = 0; e < NE; ++e) if (e != i0 && acc[e] > m1) { m1 = acc[e]; i1 = e; }

  float e1 = __expf(m1 - m0);
  float w0 = 1.f / (1.f + e1);
  float w1 = e1 * w0;

  if (lane == 0) {
    top2i[2 * t] = i0;  top2i[2 * t + 1] = i1;
    top2w[2 * t] = w0;  top2w[2 * t + 1] = w1;
  }
}

// ---------------- Count + exclusive scan (1 block) --------------------------
__global__ __launch_bounds__(256) void count_scan_kernel(
    const int* __restrict__ top2i,
    int* __restrict__ counts, int* __restrict__ offsets, int* __restrict__ cursors)
{
  __shared__ int s_cnt[NE];
  int tid = threadIdx.x;
  if (tid < NE) s_cnt[tid] = 0;
  __syncthreads();

  int c0=0,c1=0,c2=0,c3=0,c4=0,c5=0,c6=0,c7=0;
  for (int t = tid; t < TT; t += 256) {
    int e0 = top2i[2 * t], e1 = top2i[2 * t + 1];
    c0 += __popcll(__ballot(e0 == 0)) + __popcll(__ballot(e1 == 0));
    c1 += __popcll(__ballot(e0 == 1)) + __popcll(__ballot(e1 == 1));
    c2 += __popcll(__ballot(e0 == 2)) + __popcll(__ballot(e1 == 2));
    c3 += __popcll(__ballot(e0 == 3)) + __popcll(__ballot(e1 == 3));
    c4 += __popcll(__ballot(e0 == 4)) + __popcll(__ballot(e1 == 4));
    c5 += __popcll(__ballot(e0 == 5)) + __popcll(__ballot(e1 == 5));
    c6 += __popcll(__ballot(e0 == 6)) + __popcll(__ballot(e1 == 6));
    c7 += __popcll(__ballot(e0 == 7)) + __popcll(__ballot(e1 == 7));
  }
  if ((tid & 63) == 0) {
    atomicAdd(&s_cnt[0], c0); atomicAdd(&s_cnt[1], c1);
    atomicAdd(&s_cnt[2], c2); atomicAdd(&s_cnt[3], c3);
    atomicAdd(&s_cnt[4], c4); atomicAdd(&s_cnt[5], c5);
    atomicAdd(&s_cnt[6], c6); atomicAdd(&s_cnt[7], c7);
  }
  __syncthreads();
  if (tid == 0) {
    int run = 0;
    #pragma unroll
    for (int e = 0; e < NE; ++e) {
      counts[e] = s_cnt[e]; offsets[e] = run; cursors[e] = run; run += s_cnt[e];
    }
    offsets[NE] = run;
  }
}

// ---------------- Placement (wave-aggregated atomics) -----------------------
__global__ __launch_bounds__(256) void place_kernel(
    const int* __restrict__ top2i, const float* __restrict__ top2w,
    int* __restrict__ cursors,
    int* __restrict__ token_map, float* __restrict__ slot_w)
{
  int tid  = threadIdx.x;
  int lane = tid & 63;
  int t    = blockIdx.x * 256 + tid;

  #pragma unroll
  for (int k = 0; k < 2; ++k) {
    int   e = top2i[2 * t + k];
    float w = top2w[2 * t + k];
    #pragma unroll
    for (int ee = 0; ee < NE; ++ee) {
      unsigned long long m = __ballot(e == ee);
      if (e == ee) {
        int leader = __ffsll((long long)m) - 1;
        int pre    = __popcll(m & ((1ull << lane) - 1ull));
        int base   = 0;
        if (lane == leader) base = atomicAdd(&cursors[ee], (int)__popcll(m));
        base = __shfl(base, leader, 64);
        token_map[base + pre] = t;
        slot_w[base + pre]    = w;
      }
    }
  }
}

// ---------------- weight converts -------------------------------------------
__global__ __launch_bounds__(256) void cvt_wgu_kernel(
    const float* __restrict__ wg, const float* __restrict__ wu,
    unsigned short* __restrict__ wgu)
{
  int e   = blockIdx.y;
  int idx = blockIdx.x * 256 + threadIdx.x;
  int col8 = idx & 127;
  int rr   = idx >> 7;
  int blk  = rr >> 8;
  int win  = rr & 255;
  const float* srow = (win < 128)
      ? wg + ((size_t)e * ID + blk * 128 + win) * HD
      : wu + ((size_t)e * ID + blk * 128 + (win - 128)) * HD;
  const float4* p = (const float4*)(srow + col8 * 8);
  float4 a = p[0], b = p[1];
  uint4 v;
  v.x = pack_bf2(a.x, a.y); v.y = pack_bf2(a.z, a.w);
  v.z = pack_bf2(b.x, b.y); v.w = pack_bf2(b.z, b.w);
  *(uint4*)(wgu + ((size_t)e * NID2 + rr) * HD + col8 * 8) = v;
}

__global__ __launch_bounds__(256) void cvt_bf16_kernel(
    const float* __restrict__ in, unsigned short* __restrict__ out, int n8)
{
  int i = blockIdx.x * 256 + threadIdx.x;
  if (i >= n8) return;
  const float4* p = (const float4*)(in + (size_t)i * 8);
  float4 a = p[0], b = p[1];
  uint4 v;
  v.x = pack_bf2(a.x, a.y); v.y = pack_bf2(a.z, a.w);
  v.z = pack_bf2(b.x, b.y); v.w = pack_bf2(b.z, b.w);
  ((uint4*)out)[i] = v;
}

// ============================================================================
//  GEMM core: BM=128 x BN=256 x BK=64, 8 waves, 3-slot LDS ring, counted vmcnt
//  T2 (both sides): gload_lds dst is linear; SOURCE 16B-slot = (l&7)^(l>>3);
//  read byte-col = kb ^ ((lane&7)<<4).  Rows tile 32 banks 2-way (free, m136).
//  2 phases per K-step: {8 ds_read, 3 gload, 16 MFMA(setprio), barrier} x2,
//  vmcnt(6) once per K-step (tile t+1 ready, t+2 in flight).
// ============================================================================

#define STAGE_P0(t) { \
  int k0 = (t) * 64; \
  unsigned short* sb = lds + ((t) % 3) * 24576; \
  gload16(asrc[0] + k0, sb + adst[0]); \
  gload16(asrc[1] + k0, sb + adst[1]); \
  gload16(bsrc[0] + k0, sb + bdst[0]); \
  gload16(bsrc[1] + k0, sb + bdst[1]); }

#define STAGE_P1(t) { \
  int k0 = (t) * 64; \
  unsigned short* sb = lds + ((t) % 3) * 24576; \
  gload16(bsrc[2] + k0, sb + bdst[2]); \
  gload16(bsrc[3] + k0, sb + bdst[3]); }

#define PHASE(t, kk, STAGEM) { \
  const char* sa = (const char*)(lds + ((t) % 3) * 24576); \
  const char* sB = sa + 16384; \
  int kb = (kk) * 64 + kq; \
  short8 af[4], bfr[4]; \
  _Pragma("unroll") for (int m = 0; m < 4; ++m) \
    af[m] = *(const short8*)(sa + (wr * 64 + m * 16 + arow) * 128 + (kb ^ rxor)); \
  _Pragma("unroll") for (int n = 0; n < 4; ++n) \
    bfr[n] = *(const short8*)(sB + (wc * 64 + n * 16 + arow) * 128 + (kb ^ rxor)); \
  STAGEM; \
  __builtin_amdgcn_s_setprio(1); \
  _Pragma("unroll") for (int m = 0; m < 4; ++m) \
    _Pragma("unroll") for (int n = 0; n < 4; ++n) \
      acc[m][n] = __builtin_amdgcn_mfma_f32_16x16x32_bf16(af[m], bfr[n], acc[m][n], 0, 0, 0); \
  __builtin_amdgcn_s_setprio(0); }

#define KLOOP(NKT) \
  STAGE_P0(0); STAGE_P1(0); STAGE_P0(1); STAGE_P1(1); \
  asm volatile("s_waitcnt vmcnt(6)" ::: "memory"); \
  __builtin_amdgcn_s_barrier(); \
  for (int t = 0; t < (NKT) - 2; ++t) { \
    PHASE(t, 0, STAGE_P0(t + 2)); \
    __builtin_amdgcn_s_barrier(); \
    PHASE(t, 1, STAGE_P1(t + 2)); \
    asm volatile("s_waitcnt vmcnt(6)" ::: "memory"); \
    __builtin_amdgcn_s_barrier(); \
  } \
  PHASE((NKT) - 2, 0, (void)0); \
  __builtin_amdgcn_s_barrier(); \
  PHASE((NKT) - 2, 1, (void)0); \
  asm volatile("s_waitcnt vmcnt(0)" ::: "memory"); \
  __builtin_amdgcn_s_barrier(); \
  PHASE((NKT) - 1, 0, (void)0); \
  PHASE((NKT) - 1, 1, (void)0);

// GEMM1: gate/up interleaved B; epilogue exchanges up-acc via LDS, fuses silu
__global__ __launch_bounds__(512, 2) void gemm1_fast(
    const unsigned short* __restrict__ xb, const unsigned short* __restrict__ wgu,
    const int* __restrict__ counts, const int* __restrict__ offsets,
    const int* __restrict__ token_map, unsigned short* __restrict__ act)
{
  extern __shared__ char smem[];               // 147456 B
  unsigned short* lds = (unsigned short*)smem;

  int e   = blockIdx.z;
  int cnt = counts[e];
  int t0  = blockIdx.x * 128;
  if (t0 >= cnt) return;
  int y   = blockIdx.y;                        // i-block 0..21
  int off = offsets[e];

  int tid  = threadIdx.x;
  int lane = tid & 63;
  int w    = tid >> 6;
  int wr   = w >> 2;                           // 0..1
  int wc   = w & 3;                            // 0..3 (0,1=gate 2,3=up)

  int lr   = lane >> 3;
  int colE = (((lane & 7) ^ lr) << 3);         // inverse-swizzled source col
  const unsigned short* asrc[2];
  const unsigned short* bsrc[4];
  unsigned int adst[2], bdst[4];
  #pragma unroll
  for (int j = 0; j < 2; ++j) {
    int c   = 2 * w + j;
    int row = c * 8 + lr;
    int tr  = t0 + row;
    int slot = off + (tr < cnt ? tr : cnt - 1);
    asrc[j] = xb + (size_t)token_map[slot] * HD + colE;
    adst[j] = c * 512;
  }
  #pragma unroll
  for (int j = 0; j < 4; ++j) {
    int c   = 4 * w + j;
    int row = c * 8 + lr;
    bsrc[j] = wgu + ((size_t)e * NID2 + (size_t)y * 256 + row) * HD + colE;
    bdst[j] = 8192 + c * 512;
  }

  f32x4 zf = {0.f, 0.f, 0.f, 0.f};
  f32x4 acc[4][4];
  #pragma unroll
  for (int m = 0; m < 4; ++m)
    #pragma unroll
    for (int n = 0; n < 4; ++n) acc[m][n] = zf;

  int rxor = (lane & 7) << 4;                  // read-side byte xor
  int arow = lane & 15;
  int kq   = (lane >> 4) << 4;

  KLOOP(HD / 64);

  // ---- epilogue: up-waves publish acc; gate-waves fuse silu(g)*u ----
  __syncthreads();
  float* xch = (float*)smem;
  int prow = (lane >> 4) << 2;
  int pcol = lane & 15;
  if (wc >= 2) {
    float* base = xch + (size_t)((wr * 2 + (wc - 2)) * 4096);
    #pragma unroll
    for (int m = 0; m < 4; ++m)
      #pragma unroll
      for (int n = 0; n < 4; ++n)
        #pragma unroll
        for (int r = 0; r < 4; ++r)
          base[(m * 16 + prow + r) * 64 + n * 16 + pcol] = acc[m][n][r];
  }
  __syncthreads();
  if (wc < 2) {
    const float* base = xch + (size_t)((wr * 2 + wc) * 4096);
    int i0 = y * 128 + wc * 64;
    #pragma unroll
    for (int m = 0; m < 4; ++m) {
      #pragma unroll
      for (int r = 0; r < 4; ++r) {
        int row = wr * 64 + m * 16 + prow + r;
        int tr2 = t0 + row;
        if (tr2 >= cnt) continue;
        size_t obase = (size_t)(off + tr2) * ID + i0 + pcol;
        #pragma unroll
        for (int n = 0; n < 4; ++n) {
          float g = acc[m][n][r];
          float u = base[(m * 16 + prow + r) * 64 + n * 16 + pcol];
          float h = g * u / (1.f + __expf(-g));
          act[obase + n * 16] = f2bf(h);
        }
      }
    }
  }
}

// GEMM2: out[token,h] += w_slot * (act @ w_down^T)
__global__ __launch_bounds__(512, 2) void gemm2_fast(
    const unsigned short* __restrict__ act, const unsigned short* __restrict__ wdb,
    const int* __restrict__ counts, const int* __restrict__ offsets,
    const int* __restrict__ token_map, const float* __restrict__ slot_w,
    float* __restrict__ out)
{
  extern __shared__ char smem[];
  unsigned short* lds = (unsigned short*)smem;

  int e   = blockIdx.z;
  int cnt = counts[e];
  int t0  = blockIdx.x * 128;
  if (t0 >= cnt) return;
  int y   = blockIdx.y;                        // h-block 0..3
  int off = offsets[e];

  int tid  = threadIdx.x;
  int lane = tid & 63;
  int w    = tid >> 6;
  int wr   = w >> 2;
  int wc   = w & 3;

  int lr   = lane >> 3;
  int colE = (((lane & 7) ^ lr) << 3);
  const unsigned short* asrc[2];
  const unsigned short* bsrc[4];
  unsigned int adst[2], bdst[4];
  #pragma unroll
  for (int j = 0; j < 2; ++j) {
    int c   = 2 * w + j;
    int row = c * 8 + lr;
    int tr  = t0 + row;
    int slot = off + (tr < cnt ? tr : cnt - 1);
    asrc[j] = act + (size_t)slot * ID + colE;
    adst[j] = c * 512;
  }
  #pragma unroll
  for (int j = 0; j < 4; ++j) {
    int c   = 4 * w + j;
    int row = c * 8 + lr;
    bsrc[j] = wdb + ((size_t)e * HD + (size_t)y * 256 + row) * ID + colE;
    bdst[j] = 8192 + c * 512;
  }

  f32x4 zf = {0.f, 0.f, 0.f, 0.f};
  f32x4 acc[4][4];
  #pragma unroll
  for (int m = 0; m < 4; ++m)
    #pragma unroll
    for (int n = 0; n < 4; ++n) acc[m][n] = zf;

  int rxor = (lane & 7) << 4;
  int arow = lane & 15;
  int kq   = (lane >> 4) << 4;

  KLOOP(ID / 64);

  int prow = (lane >> 4) << 2;
  int pcol = lane & 15;
  #pragma unroll
  for (int m = 0; m < 4; ++m) {
    #pragma unroll
    for (int r = 0; r < 4; ++r) {
      int row = wr * 64 + m * 16 + prow + r;
      int tr2 = t0 + row;
      if (tr2 >= cnt) continue;
      int slot = off + tr2;
      float wsl = slot_w[slot];
      float* ob = out + (size_t)token_map[slot] * HD + y * 256 + wc * 64 + pcol;
      #pragma unroll
      for (int n = 0; n < 4; ++n)
        atomicAdd(ob + n * 16, acc[m][n][r] * wsl);
    }
  }
}

// ---------------- launch ----------------------------------------------------
extern "C" void kernel_launch(void* const* d_in, const int* in_sizes, int n_in,
                              void* d_out, int out_size, void* d_ws, size_t ws_size,
                              hipStream_t stream) {
  const float* x        = (const float*)d_in[0];
  const float* w_router = (const float*)d_in[1];
  const float* w_gate   = (const float*)d_in[2];
  const float* w_up     = (const float*)d_in[3];
  const float* w_down   = (const float*)d_in[4];

  char* ws = (char*)d_ws;
  int*   top2i   = (int*)(ws + WS_TOP2I);
  float* top2w   = (float*)(ws + WS_TOP2W);
  int*   counts  = (int*)(ws + WS_CNT);
  int*   offsets = (int*)(ws + WS_OFF);
  int*   cursors = (int*)(ws + WS_CUR);
  int*   tmap    = (int*)(ws + WS_TMAP);
  float* slotw   = (float*)(ws + WS_SLOTW);
  unsigned short* xb  = (unsigned short*)(ws + WS_XB);
  unsigned short* wgu = (unsigned short*)(ws + WS_WGU);
  unsigned short* wdb = (unsigned short*)(ws + WS_WDB);
  unsigned short* act = (unsigned short*)(ws + WS_ACT);

  hipFuncSetAttribute((const void*)gemm1_fast,
                      hipFuncAttributeMaxDynamicSharedMemorySize, 147456);
  hipFuncSetAttribute((const void*)gemm2_fast,
                      hipFuncAttributeMaxDynamicSharedMemorySize, 147456);

  hipMemsetAsync(d_out, 0, (size_t)out_size * sizeof(float), stream);
  router_kernel<<<TT / 4, 256, 0, stream>>>(x, w_router, top2i, top2w, xb);
  count_scan_kernel<<<1, 256, 0, stream>>>(top2i, counts, offsets, cursors);
  place_kernel<<<TT / 256, 256, 0, stream>>>(top2i, top2w, cursors, tmap, slotw);
  cvt_wgu_kernel<<<dim3(2816, NE), 256, 0, stream>>>(w_gate, w_up, wgu);
  cvt_bf16_kernel<<<11264, 256, 0, stream>>>(w_down, wdb, NE * HD * ID / 8);

  gemm1_fast<<<dim3(64, 22, NE), 512, 147456, stream>>>(xb, wgu, counts, offsets, tmap, act);
  gemm2_fast<<<dim3(64, 4, NE), 512, 147456, stream>>>(act, wdb, counts, offsets, tmap, slotw, (float*)d_out);
}

// Round 5
// 583.423 us; speedup vs baseline: 2.8073x; 1.3719x over previous
//
#include <hip/hip_runtime.h>

#define TT 8192   // tokens
#define HD 1024   // hidden
#define ID 2816   // intermediate
#define NE 8      // experts
#define NID2 (2*ID)   // 5632 interleaved gate/up rows per expert

typedef __attribute__((ext_vector_type(8))) short short8;
typedef __attribute__((ext_vector_type(4))) float f32x4;

// ---------------- ws layout --------------------------------------------------
#define WS_TOP2I 0
#define WS_TOP2W 65536
#define WS_CNT   131072
#define WS_OFF   131136
#define WS_CUR   131200
#define WS_TMAP  131328
#define WS_SLOTW 196864
#define WS_T2S   262400                      // tok2slot, 64 KB
#define WS_XB    1048576ULL                  // x bf16, 16 MB
#define WS_WGU   (WS_XB  + 16777216ULL)      // interleaved gate/up bf16, 92.3 MB (down_out aliases this)
#define WS_WDB   (WS_WGU + 92274688ULL)      // w_down bf16, 46.1 MB
#define WS_ACT   (WS_WDB + 46137344ULL)      // act bf16, 92.3 MB

__device__ __forceinline__ unsigned int pack_bf2(float lo, float hi) {
  unsigned int ul = __builtin_bit_cast(unsigned int, lo) + 0x8000u;
  unsigned int uh = __builtin_bit_cast(unsigned int, hi) + 0x8000u;
  return (uh & 0xffff0000u) | (ul >> 16);
}

__device__ __forceinline__ unsigned short f2bf(float f) {
  unsigned int u = __builtin_bit_cast(unsigned int, f);
  return (unsigned short)((u + 0x8000u) >> 16);
}

__device__ __forceinline__ void gload16(const void* g, void* l) {
  __builtin_amdgcn_global_load_lds(
      (const __attribute__((address_space(1))) unsigned int*)g,
      (__attribute__((address_space(3))) unsigned int*)l, 16, 0, 0);
}

// ---------------- Router: fp32 logits, top-2; also emits x as bf16 ----------
__global__ __launch_bounds__(256) void router_kernel(
    const float* __restrict__ x, const float* __restrict__ wr,
    int* __restrict__ top2i, float* __restrict__ top2w,
    unsigned short* __restrict__ xb)
{
  int tid  = threadIdx.x;
  int lane = tid & 63;
  int t    = blockIdx.x * 4 + (tid >> 6);

  const float4* xp = (const float4*)(x + (size_t)t * HD + lane * 16);
  float4 xv[4];
  #pragma unroll
  for (int j = 0; j < 4; ++j) xv[j] = xp[j];

  uint4 v0, v1;
  v0.x = pack_bf2(xv[0].x, xv[0].y); v0.y = pack_bf2(xv[0].z, xv[0].w);
  v0.z = pack_bf2(xv[1].x, xv[1].y); v0.w = pack_bf2(xv[1].z, xv[1].w);
  v1.x = pack_bf2(xv[2].x, xv[2].y); v1.y = pack_bf2(xv[2].z, xv[2].w);
  v1.z = pack_bf2(xv[3].x, xv[3].y); v1.w = pack_bf2(xv[3].z, xv[3].w);
  uint4* xrow = (uint4*)(xb + (size_t)t * HD + lane * 16);
  xrow[0] = v0; xrow[1] = v1;

  float acc[NE];
  #pragma unroll
  for (int e = 0; e < NE; ++e) {
    const float4* wp = (const float4*)(wr + (size_t)e * HD + lane * 16);
    float s = 0.f;
    #pragma unroll
    for (int j = 0; j < 4; ++j) {
      float4 w = wp[j];
      s += xv[j].x * w.x + xv[j].y * w.y + xv[j].z * w.z + xv[j].w * w.w;
    }
    acc[e] = s;
  }
  #pragma unroll
  for (int d = 1; d < 64; d <<= 1) {
    #pragma unroll
    for (int e = 0; e < NE; ++e) acc[e] += __shfl_xor(acc[e], d, 64);
  }
  int   i0 = 0; float m0 = acc[0];
  #pragma unroll
  for (int e = 1; e < NE; ++e) if (acc[e] > m0) { m0 = acc[e]; i0 = e; }
  int   i1 = -1; float m1 = -3.4e38f;
  #pragma unroll
  for (int e = 0; e < NE; ++e) if (e != i0 && acc[e] > m1) { m1 = acc[e]; i1 = e; }

  float e1 = __expf(m1 - m0);
  float w0 = 1.f / (1.f + e1);
  float w1 = e1 * w0;

  if (lane == 0) {
    top2i[2 * t] = i0;  top2i[2 * t + 1] = i1;
    top2w[2 * t] = w0;  top2w[2 * t + 1] = w1;
  }
}

// ---------------- Count + exclusive scan (1 block) --------------------------
__global__ __launch_bounds__(256) void count_scan_kernel(
    const int* __restrict__ top2i,
    int* __restrict__ counts, int* __restrict__ offsets, int* __restrict__ cursors)
{
  __shared__ int s_cnt[NE];
  int tid = threadIdx.x;
  if (tid < NE) s_cnt[tid] = 0;
  __syncthreads();

  int c0=0,c1=0,c2=0,c3=0,c4=0,c5=0,c6=0,c7=0;
  for (int t = tid; t < TT; t += 256) {
    int e0 = top2i[2 * t], e1 = top2i[2 * t + 1];
    c0 += __popcll(__ballot(e0 == 0)) + __popcll(__ballot(e1 == 0));
    c1 += __popcll(__ballot(e0 == 1)) + __popcll(__ballot(e1 == 1));
    c2 += __popcll(__ballot(e0 == 2)) + __popcll(__ballot(e1 == 2));
    c3 += __popcll(__ballot(e0 == 3)) + __popcll(__ballot(e1 == 3));
    c4 += __popcll(__ballot(e0 == 4)) + __popcll(__ballot(e1 == 4));
    c5 += __popcll(__ballot(e0 == 5)) + __popcll(__ballot(e1 == 5));
    c6 += __popcll(__ballot(e0 == 6)) + __popcll(__ballot(e1 == 6));
    c7 += __popcll(__ballot(e0 == 7)) + __popcll(__ballot(e1 == 7));
  }
  if ((tid & 63) == 0) {
    atomicAdd(&s_cnt[0], c0); atomicAdd(&s_cnt[1], c1);
    atomicAdd(&s_cnt[2], c2); atomicAdd(&s_cnt[3], c3);
    atomicAdd(&s_cnt[4], c4); atomicAdd(&s_cnt[5], c5);
    atomicAdd(&s_cnt[6], c6); atomicAdd(&s_cnt[7], c7);
  }
  __syncthreads();
  if (tid == 0) {
    int run = 0;
    #pragma unroll
    for (int e = 0; e < NE; ++e) {
      counts[e] = s_cnt[e]; offsets[e] = run; cursors[e] = run; run += s_cnt[e];
    }
    offsets[NE] = run;
  }
}

// ---------------- Placement (wave-aggregated atomics) -----------------------
__global__ __launch_bounds__(256) void place_kernel(
    const int* __restrict__ top2i, const float* __restrict__ top2w,
    int* __restrict__ cursors,
    int* __restrict__ token_map, float* __restrict__ slot_w, int* __restrict__ tok2slot)
{
  int tid  = threadIdx.x;
  int lane = tid & 63;
  int t    = blockIdx.x * 256 + tid;

  #pragma unroll
  for (int k = 0; k < 2; ++k) {
    int   e = top2i[2 * t + k];
    float w = top2w[2 * t + k];
    #pragma unroll
    for (int ee = 0; ee < NE; ++ee) {
      unsigned long long m = __ballot(e == ee);
      if (e == ee) {
        int leader = __ffsll((long long)m) - 1;
        int pre    = __popcll(m & ((1ull << lane) - 1ull));
        int base   = 0;
        if (lane == leader) base = atomicAdd(&cursors[ee], (int)__popcll(m));
        base = __shfl(base, leader, 64);
        token_map[base + pre] = t;
        slot_w[base + pre]    = w;
        tok2slot[2 * t + k]   = base + pre;
      }
    }
  }
}

// ---------------- weight converts -------------------------------------------
__global__ __launch_bounds__(256) void cvt_wgu_kernel(
    const float* __restrict__ wg, const float* __restrict__ wu,
    unsigned short* __restrict__ wgu)
{
  int e   = blockIdx.y;
  int idx = blockIdx.x * 256 + threadIdx.x;
  int col8 = idx & 127;
  int rr   = idx >> 7;
  int blk  = rr >> 8;
  int win  = rr & 255;
  const float* srow = (win < 128)
      ? wg + ((size_t)e * ID + blk * 128 + win) * HD
      : wu + ((size_t)e * ID + blk * 128 + (win - 128)) * HD;
  const float4* p = (const float4*)(srow + col8 * 8);
  float4 a = p[0], b = p[1];
  uint4 v;
  v.x = pack_bf2(a.x, a.y); v.y = pack_bf2(a.z, a.w);
  v.z = pack_bf2(b.x, b.y); v.w = pack_bf2(b.z, b.w);
  *(uint4*)(wgu + ((size_t)e * NID2 + rr) * HD + col8 * 8) = v;
}

__global__ __launch_bounds__(256) void cvt_bf16_kernel(
    const float* __restrict__ in, unsigned short* __restrict__ out, int n8)
{
  int i = blockIdx.x * 256 + threadIdx.x;
  if (i >= n8) return;
  const float4* p = (const float4*)(in + (size_t)i * 8);
  float4 a = p[0], b = p[1];
  uint4 v;
  v.x = pack_bf2(a.x, a.y); v.y = pack_bf2(a.z, a.w);
  v.z = pack_bf2(b.x, b.y); v.w = pack_bf2(b.z, b.w);
  ((uint4*)out)[i] = v;
}

// ============================================================================
//  GEMM core: BM=256 x BN=256 x BK=64, 8 waves (2M x 4N), per-wave 128x64 out.
//  LDS 128KB: buf[2] x (A[256][64] + B[256][64]) bf16, slot-swizzled
//  (LDS[r][s] = G[r][s^(r&7)], via pre-swizzled source col; read xor (lane&7)<<4).
//  Per K-tile: stage(t+1) 8 x gload16 at top, 24 ds_read_b128, 64 MFMA
//  (setprio-wrapped), then vmcnt(0)+s_barrier — loads age a full tile before wait.
// ============================================================================

#define STAGE8(t) { \
    size_t k1 = (size_t)((t) * 64); \
    char* db = ldsc + (((t) & 1) ? 65536u : 0u) + (unsigned)tid * 16; \
    gload16(aS[0] + k1, db);           gload16(aS[1] + k1, db + 8192); \
    gload16(aS[2] + k1, db + 16384);   gload16(aS[3] + k1, db + 24576); \
    gload16(bS[0] + k1, db + 32768);   gload16(bS[1] + k1, db + 40960); \
    gload16(bS[2] + k1, db + 49152);   gload16(bS[3] + k1, db + 57344); }

#define KTILE_BODY(t, NKT) { \
    if ((t) + 1 < (NKT)) STAGE8((t) + 1); \
    const char* sa = ldsc + (((t) & 1) ? 65536u : 0u); \
    const char* sb = sa + 32768; \
    _Pragma("unroll") for (int kk = 0; kk < 2; ++kk) { \
      int kb = kk * 64 + kq; \
      short8 bfr[4], af[8]; \
      _Pragma("unroll") for (int n = 0; n < 4; ++n) \
        bfr[n] = *(const short8*)(sb + (wc * 64 + n * 16 + arow) * 128 + (kb ^ rxor)); \
      _Pragma("unroll") for (int m = 0; m < 8; ++m) \
        af[m] = *(const short8*)(sa + (wr * 128 + m * 16 + arow) * 128 + (kb ^ rxor)); \
      __builtin_amdgcn_s_setprio(1); \
      _Pragma("unroll") for (int m = 0; m < 8; ++m) \
        _Pragma("unroll") for (int n = 0; n < 4; ++n) \
          acc[m][n] = __builtin_amdgcn_mfma_f32_16x16x32_bf16(af[m], bfr[n], acc[m][n], 0, 0, 0); \
      __builtin_amdgcn_s_setprio(0); \
    } \
    asm volatile("s_waitcnt vmcnt(0)" ::: "memory"); \
    __builtin_amdgcn_s_barrier(); }

// bijective XCD swizzle (m204); nwg % 8 == 0 for both gemm grids
#define XCD_DECODE(NX, NY) \
  int nwg  = (NX) * (NY) * NE; \
  int flat = blockIdx.x + (NX) * (blockIdx.y + (NY) * blockIdx.z); \
  int qq   = nwg >> 3; \
  int wg   = (flat & 7) * qq + (flat >> 3); \
  int bx   = wg % (NX); \
  int rem  = wg / (NX); \
  int y    = rem % (NY); \
  int e    = rem / (NY);

// GEMM1: act[slot, i] = silu(gate) * up, gate/up from interleaved wgu
__global__ __launch_bounds__(512, 2) void gemm1_fast(
    const unsigned short* __restrict__ xb, const unsigned short* __restrict__ wgu,
    const int* __restrict__ counts, const int* __restrict__ offsets,
    const int* __restrict__ token_map, unsigned short* __restrict__ act)
{
  extern __shared__ char smem[];               // 131072 B
  char* ldsc = smem;

  XCD_DECODE(16, 22)
  int cnt = counts[e];
  int off = offsets[e];

  int tid  = threadIdx.x;
  int lane = tid & 63;
  int w    = tid >> 6;
  int wr   = w >> 2;                           // 0..1 (M half)
  int wc   = w & 3;                            // 0..3 (N quarter; 0,1=gate 2,3=up)

  int srow0 = tid >> 3;                        // 0..63
  int colE  = (((tid & 7) ^ ((tid >> 3) & 7)) << 3);
  int rxor  = (lane & 7) << 4;
  int arow  = lane & 15;
  int kq    = (lane >> 4) << 4;
  int prow  = (lane >> 4) << 2;

  for (int t0 = bx * 256; t0 < cnt; t0 += 4096) {
    const unsigned short* aS[4];
    const unsigned short* bS[4];
    #pragma unroll
    for (int j = 0; j < 4; ++j) {
      int row  = srow0 + 64 * j;
      int tr   = t0 + row;
      int slot = off + (tr < cnt ? tr : cnt - 1);
      aS[j] = xb  + (size_t)token_map[slot] * HD + colE;
      bS[j] = wgu + ((size_t)e * NID2 + (size_t)y * 256 + row) * HD + colE;
    }

    f32x4 zf = {0.f, 0.f, 0.f, 0.f};
    f32x4 acc[8][4];
    #pragma unroll
    for (int m = 0; m < 8; ++m)
      #pragma unroll
      for (int n = 0; n < 4; ++n) acc[m][n] = zf;

    STAGE8(0);
    asm volatile("s_waitcnt vmcnt(0)" ::: "memory");
    __builtin_amdgcn_s_barrier();
    for (int t = 0; t < HD / 64; ++t) KTILE_BODY(t, HD / 64);

    // ---- epilogue: up-waves publish acc via LDS; gate-waves fuse silu ----
    __syncthreads();
    float* xch = (float*)smem;                 // 4 regions x 32KB (128x64 f32)
    if (wc >= 2) {
      float* base = xch + (size_t)((wr * 2 + (wc - 2)) * 8192);
      #pragma unroll
      for (int m = 0; m < 8; ++m)
        #pragma unroll
        for (int n = 0; n < 4; ++n)
          #pragma unroll
          for (int r = 0; r < 4; ++r)
            base[(m * 16 + prow + r) * 64 + n * 16 + arow] = acc[m][n][r];
    }
    __syncthreads();
    if (wc < 2) {
      const float* base = xch + (size_t)((wr * 2 + wc) * 8192);
      int i0 = y * 128 + wc * 64;
      #pragma unroll
      for (int m = 0; m < 8; ++m) {
        #pragma unroll
        for (int r = 0; r < 4; ++r) {
          int row = wr * 128 + m * 16 + prow + r;
          int tr2 = t0 + row;
          if (tr2 >= cnt) continue;
          size_t ob = (size_t)(off + tr2) * ID + i0 + arow;
          #pragma unroll
          for (int n = 0; n < 4; ++n) {
            float g = acc[m][n][r];
            float u = base[(m * 16 + prow + r) * 64 + n * 16 + arow];
            float h = g * u / (1.f + __expf(-g));
            act[ob + n * 16] = f2bf(h);
          }
        }
      }
    }
    __syncthreads();
  }
}

// GEMM2: down[slot, h] = act @ w_down^T   (combine applies router weights)
__global__ __launch_bounds__(512, 2) void gemm2_fast(
    const unsigned short* __restrict__ act, const unsigned short* __restrict__ wdb,
    const int* __restrict__ counts, const int* __restrict__ offsets,
    float* __restrict__ down)
{
  extern __shared__ char smem[];
  char* ldsc = smem;

  XCD_DECODE(16, 4)
  int cnt = counts[e];
  int off = offsets[e];

  int tid  = threadIdx.x;
  int lane = tid & 63;
  int w    = tid >> 6;
  int wr   = w >> 2;
  int wc   = w & 3;

  int srow0 = tid >> 3;
  int colE  = (((tid & 7) ^ ((tid >> 3) & 7)) << 3);
  int rxor  = (lane & 7) << 4;
  int arow  = lane & 15;
  int kq    = (lane >> 4) << 4;
  int prow  = (lane >> 4) << 2;

  for (int t0 = bx * 256; t0 < cnt; t0 += 4096) {
    const unsigned short* aS[4];
    const unsigned short* bS[4];
    #pragma unroll
    for (int j = 0; j < 4; ++j) {
      int row  = srow0 + 64 * j;
      int tr   = t0 + row;
      int slot = off + (tr < cnt ? tr : cnt - 1);
      aS[j] = act + (size_t)slot * ID + colE;
      bS[j] = wdb + ((size_t)e * HD + (size_t)y * 256 + row) * ID + colE;
    }

    f32x4 zf = {0.f, 0.f, 0.f, 0.f};
    f32x4 acc[8][4];
    #pragma unroll
    for (int m = 0; m < 8; ++m)
      #pragma unroll
      for (int n = 0; n < 4; ++n) acc[m][n] = zf;

    STAGE8(0);
    asm volatile("s_waitcnt vmcnt(0)" ::: "memory");
    __builtin_amdgcn_s_barrier();
    for (int t = 0; t < ID / 64; ++t) KTILE_BODY(t, ID / 64);

    #pragma unroll
    for (int m = 0; m < 8; ++m) {
      #pragma unroll
      for (int r = 0; r < 4; ++r) {
        int row = wr * 128 + m * 16 + prow + r;
        int tr2 = t0 + row;
        if (tr2 >= cnt) continue;
        float* ob = down + (size_t)(off + tr2) * HD + (size_t)y * 256 + wc * 64 + arow;
        #pragma unroll
        for (int n = 0; n < 4; ++n)
          ob[n * 16] = acc[m][n][r];
      }
    }
  }
}

// ---------------- combine: out[t] = w0*down[s0] + w1*down[s1] ---------------
__global__ __launch_bounds__(256) void combine_kernel(
    const float* __restrict__ down, const float* __restrict__ slot_w,
    const int* __restrict__ tok2slot, float* __restrict__ out)
{
  int t   = blockIdx.x;
  int tid = threadIdx.x;
  int s0  = tok2slot[2 * t], s1 = tok2slot[2 * t + 1];
  float w0 = slot_w[s0], w1 = slot_w[s1];
  const float4* d0 = (const float4*)(down + (size_t)s0 * HD) + tid;
  const float4* d1 = (const float4*)(down + (size_t)s1 * HD) + tid;
  float4 a = *d0, b = *d1;
  float4 o;
  o.x = w0 * a.x + w1 * b.x;  o.y = w0 * a.y + w1 * b.y;
  o.z = w0 * a.z + w1 * b.z;  o.w = w0 * a.w + w1 * b.w;
  ((float4*)(out + (size_t)t * HD))[tid] = o;
}

// ---------------- launch ----------------------------------------------------
extern "C" void kernel_launch(void* const* d_in, const int* in_sizes, int n_in,
                              void* d_out, int out_size, void* d_ws, size_t ws_size,
                              hipStream_t stream) {
  const float* x        = (const float*)d_in[0];
  const float* w_router = (const float*)d_in[1];
  const float* w_gate   = (const float*)d_in[2];
  const float* w_up     = (const float*)d_in[3];
  const float* w_down   = (const float*)d_in[4];

  char* ws = (char*)d_ws;
  int*   top2i    = (int*)(ws + WS_TOP2I);
  float* top2w    = (float*)(ws + WS_TOP2W);
  int*   counts   = (int*)(ws + WS_CNT);
  int*   offsets  = (int*)(ws + WS_OFF);
  int*   cursors  = (int*)(ws + WS_CUR);
  int*   tmap     = (int*)(ws + WS_TMAP);
  float* slotw    = (float*)(ws + WS_SLOTW);
  int*   tok2slot = (int*)(ws + WS_T2S);
  unsigned short* xb  = (unsigned short*)(ws + WS_XB);
  unsigned short* wgu = (unsigned short*)(ws + WS_WGU);
  unsigned short* wdb = (unsigned short*)(ws + WS_WDB);
  unsigned short* act = (unsigned short*)(ws + WS_ACT);
  float*          down = (float*)(ws + WS_WGU);   // aliases wgu (dead after gemm1)

  hipFuncSetAttribute((const void*)gemm1_fast,
                      hipFuncAttributeMaxDynamicSharedMemorySize, 131072);
  hipFuncSetAttribute((const void*)gemm2_fast,
                      hipFuncAttributeMaxDynamicSharedMemorySize, 131072);

  router_kernel<<<TT / 4, 256, 0, stream>>>(x, w_router, top2i, top2w, xb);
  count_scan_kernel<<<1, 256, 0, stream>>>(top2i, counts, offsets, cursors);
  place_kernel<<<TT / 256, 256, 0, stream>>>(top2i, top2w, cursors, tmap, slotw, tok2slot);
  cvt_wgu_kernel<<<dim3(2816, NE), 256, 0, stream>>>(w_gate, w_up, wgu);
  cvt_bf16_kernel<<<11264, 256, 0, stream>>>(w_down, wdb, NE * HD * ID / 8);

  gemm1_fast<<<dim3(16, 22, NE), 512, 131072, stream>>>(xb, wgu, counts, offsets, tmap, act);
  gemm2_fast<<<dim3(16, 4, NE), 512, 131072, stream>>>(act, wdb, counts, offsets, down);
  combine_kernel<<<TT, 256, 0, stream>>>(down, slotw, tok2slot, (float*)d_out);
}

// Round 6
// 564.773 us; speedup vs baseline: 2.9000x; 1.0330x over previous
//
#include <hip/hip_runtime.h>

#define TT 8192   // tokens
#define HD 1024   // hidden
#define ID 2816   // intermediate
#define NE 8      // experts
#define NID2 (2*ID)   // 5632 interleaved gate/up rows per expert

typedef __attribute__((ext_vector_type(8))) short short8;
typedef __attribute__((ext_vector_type(4))) float f32x4;

// ---------------- ws layout --------------------------------------------------
#define WS_TOP2I 0
#define WS_TOP2W 65536
#define WS_CNT   131072
#define WS_OFF   131136
#define WS_CUR   131200
#define WS_TMAP  131328
#define WS_SLOTW 196864
#define WS_T2S   262400                      // tok2slot, 64 KB
#define WS_XB    1048576ULL                  // x bf16, 16 MB
#define WS_WGU   (WS_XB  + 16777216ULL)      // interleaved gate/up bf16 (down aliases)
#define WS_WDB   (WS_WGU + 92274688ULL)      // w_down bf16, 46.1 MB
#define WS_ACT   (WS_WDB + 46137344ULL)      // act bf16, 92.3 MB

__device__ __forceinline__ unsigned int pack_bf2(float lo, float hi) {
  unsigned int ul = __builtin_bit_cast(unsigned int, lo) + 0x8000u;
  unsigned int uh = __builtin_bit_cast(unsigned int, hi) + 0x8000u;
  return (uh & 0xffff0000u) | (ul >> 16);
}

__device__ __forceinline__ unsigned short f2bf(float f) {
  unsigned int u = __builtin_bit_cast(unsigned int, f);
  return (unsigned short)((u + 0x8000u) >> 16);
}

__device__ __forceinline__ void gload16(const void* g, void* l) {
  __builtin_amdgcn_global_load_lds(
      (const __attribute__((address_space(1))) unsigned int*)g,
      (__attribute__((address_space(3))) unsigned int*)l, 16, 0, 0);
}

// ---------------- Router: fp32 logits, top-2; also emits x as bf16 ----------
__global__ __launch_bounds__(256) void router_kernel(
    const float* __restrict__ x, const float* __restrict__ wr,
    int* __restrict__ top2i, float* __restrict__ top2w,
    unsigned short* __restrict__ xb)
{
  int tid  = threadIdx.x;
  int lane = tid & 63;
  int t    = blockIdx.x * 4 + (tid >> 6);

  const float4* xp = (const float4*)(x + (size_t)t * HD + lane * 16);
  float4 xv[4];
  #pragma unroll
  for (int j = 0; j < 4; ++j) xv[j] = xp[j];

  uint4 v0, v1;
  v0.x = pack_bf2(xv[0].x, xv[0].y); v0.y = pack_bf2(xv[0].z, xv[0].w);
  v0.z = pack_bf2(xv[1].x, xv[1].y); v0.w = pack_bf2(xv[1].z, xv[1].w);
  v1.x = pack_bf2(xv[2].x, xv[2].y); v1.y = pack_bf2(xv[2].z, xv[2].w);
  v1.z = pack_bf2(xv[3].x, xv[3].y); v1.w = pack_bf2(xv[3].z, xv[3].w);
  uint4* xrow = (uint4*)(xb + (size_t)t * HD + lane * 16);
  xrow[0] = v0; xrow[1] = v1;

  float acc[NE];
  #pragma unroll
  for (int e = 0; e < NE; ++e) {
    const float4* wp = (const float4*)(wr + (size_t)e * HD + lane * 16);
    float s = 0.f;
    #pragma unroll
    for (int j = 0; j < 4; ++j) {
      float4 w = wp[j];
      s += xv[j].x * w.x + xv[j].y * w.y + xv[j].z * w.z + xv[j].w * w.w;
    }
    acc[e] = s;
  }
  #pragma unroll
  for (int d = 1; d < 64; d <<= 1) {
    #pragma unroll
    for (int e = 0; e < NE; ++e) acc[e] += __shfl_xor(acc[e], d, 64);
  }
  int   i0 = 0; float m0 = acc[0];
  #pragma unroll
  for (int e = 1; e < NE; ++e) if (acc[e] > m0) { m0 = acc[e]; i0 = e; }
  int   i1 = -1; float m1 = -3.4e38f;
  #pragma unroll
  for (int e = 0; e < NE; ++e) if (e != i0 && acc[e] > m1) { m1 = acc[e]; i1 = e; }

  float e1 = __expf(m1 - m0);
  float w0 = 1.f / (1.f + e1);
  float w1 = e1 * w0;

  if (lane == 0) {
    top2i[2 * t] = i0;  top2i[2 * t + 1] = i1;
    top2w[2 * t] = w0;  top2w[2 * t + 1] = w1;
  }
}

// ---------------- Count + exclusive scan (1 block) --------------------------
__global__ __launch_bounds__(256) void count_scan_kernel(
    const int* __restrict__ top2i,
    int* __restrict__ counts, int* __restrict__ offsets, int* __restrict__ cursors)
{
  __shared__ int s_cnt[NE];
  int tid = threadIdx.x;
  if (tid < NE) s_cnt[tid] = 0;
  __syncthreads();

  int c0=0,c1=0,c2=0,c3=0,c4=0,c5=0,c6=0,c7=0;
  for (int t = tid; t < TT; t += 256) {
    int e0 = top2i[2 * t], e1 = top2i[2 * t + 1];
    c0 += __popcll(__ballot(e0 == 0)) + __popcll(__ballot(e1 == 0));
    c1 += __popcll(__ballot(e0 == 1)) + __popcll(__ballot(e1 == 1));
    c2 += __popcll(__ballot(e0 == 2)) + __popcll(__ballot(e1 == 2));
    c3 += __popcll(__ballot(e0 == 3)) + __popcll(__ballot(e1 == 3));
    c4 += __popcll(__ballot(e0 == 4)) + __popcll(__ballot(e1 == 4));
    c5 += __popcll(__ballot(e0 == 5)) + __popcll(__ballot(e1 == 5));
    c6 += __popcll(__ballot(e0 == 6)) + __popcll(__ballot(e1 == 6));
    c7 += __popcll(__ballot(e0 == 7)) + __popcll(__ballot(e1 == 7));
  }
  if ((tid & 63) == 0) {
    atomicAdd(&s_cnt[0], c0); atomicAdd(&s_cnt[1], c1);
    atomicAdd(&s_cnt[2], c2); atomicAdd(&s_cnt[3], c3);
    atomicAdd(&s_cnt[4], c4); atomicAdd(&s_cnt[5], c5);
    atomicAdd(&s_cnt[6], c6); atomicAdd(&s_cnt[7], c7);
  }
  __syncthreads();
  if (tid == 0) {
    int run = 0;
    #pragma unroll
    for (int e = 0; e < NE; ++e) {
      counts[e] = s_cnt[e]; offsets[e] = run; cursors[e] = run; run += s_cnt[e];
    }
    offsets[NE] = run;
  }
}

// ---------------- Placement (wave-aggregated atomics) -----------------------
__global__ __launch_bounds__(256) void place_kernel(
    const int* __restrict__ top2i, const float* __restrict__ top2w,
    int* __restrict__ cursors,
    int* __restrict__ token_map, float* __restrict__ slot_w, int* __restrict__ tok2slot)
{
  int tid  = threadIdx.x;
  int lane = tid & 63;
  int t    = blockIdx.x * 256 + tid;

  #pragma unroll
  for (int k = 0; k < 2; ++k) {
    int   e = top2i[2 * t + k];
    float w = top2w[2 * t + k];
    #pragma unroll
    for (int ee = 0; ee < NE; ++ee) {
      unsigned long long m = __ballot(e == ee);
      if (e == ee) {
        int leader = __ffsll((long long)m) - 1;
        int pre    = __popcll(m & ((1ull << lane) - 1ull));
        int base   = 0;
        if (lane == leader) base = atomicAdd(&cursors[ee], (int)__popcll(m));
        base = __shfl(base, leader, 64);
        token_map[base + pre] = t;
        slot_w[base + pre]    = w;
        tok2slot[2 * t + k]   = base + pre;
      }
    }
  }
}

// ---------------- weight converts -------------------------------------------
__global__ __launch_bounds__(256) void cvt_wgu_kernel(
    const float* __restrict__ wg, const float* __restrict__ wu,
    unsigned short* __restrict__ wgu)
{
  int e   = blockIdx.y;
  int idx = blockIdx.x * 256 + threadIdx.x;
  int col8 = idx & 127;
  int rr   = idx >> 7;
  int blk  = rr >> 8;
  int win  = rr & 255;
  const float* srow = (win < 128)
      ? wg + ((size_t)e * ID + blk * 128 + win) * HD
      : wu + ((size_t)e * ID + blk * 128 + (win - 128)) * HD;
  const float4* p = (const float4*)(srow + col8 * 8);
  float4 a = p[0], b = p[1];
  uint4 v;
  v.x = pack_bf2(a.x, a.y); v.y = pack_bf2(a.z, a.w);
  v.z = pack_bf2(b.x, b.y); v.w = pack_bf2(b.z, b.w);
  *(uint4*)(wgu + ((size_t)e * NID2 + rr) * HD + col8 * 8) = v;
}

__global__ __launch_bounds__(256) void cvt_bf16_kernel(
    const float* __restrict__ in, unsigned short* __restrict__ out, int n8)
{
  int i = blockIdx.x * 256 + threadIdx.x;
  if (i >= n8) return;
  const float4* p = (const float4*)(in + (size_t)i * 8);
  float4 a = p[0], b = p[1];
  uint4 v;
  v.x = pack_bf2(a.x, a.y); v.y = pack_bf2(a.z, a.w);
  v.z = pack_bf2(b.x, b.y); v.w = pack_bf2(b.z, b.w);
  ((uint4*)out)[i] = v;
}

// ============================================================================
//  GEMM core: BM=256 x BN=256 x BK=64, 8 waves (2M x 4N), per-wave 128x64 out.
//  LDS 128KB: buf[2] x (A[256][64] + B[256][64]) bf16, slot-swizzled.
//  Counted-vmcnt 4-phase K-tile (T3+T4): issue order B01|B23|A02|A13 (2/phase),
//  ph0 waits vmcnt(2) for {B all, A0,A2}, ph1 waits vmcnt(2) for {A1,A3};
//  ph2/ph3 no wait/barrier. All issues sit after a barrier that dominates all
//  reads of the buffer being overwritten -> race-free.
// ============================================================================

#define ISSUE2(t1, j0, j1, SRC, DOFF) { \
    size_t k1 = (size_t)((t1) * 64); \
    char* db = ldsc + (((t1) & 1) ? 65536u : 0u) + (unsigned)tid * 16 + (DOFF); \
    gload16(SRC[j0] + k1, db + (j0) * 8192); \
    gload16(SRC[j1] + k1, db + (j1) * 8192); }

#define ISSUE_B01(t1) ISSUE2(t1, 0, 1, bS, 32768u)
#define ISSUE_B23(t1) ISSUE2(t1, 2, 3, bS, 32768u)
#define ISSUE_A02(t1) ISSUE2(t1, 0, 2, aS, 0u)
#define ISSUE_A13(t1) ISSUE2(t1, 1, 3, aS, 0u)

#define MFMA16(MBASE) \
    __builtin_amdgcn_s_setprio(1); \
    _Pragma("unroll") for (int m = 0; m < 4; ++m) \
      _Pragma("unroll") for (int n = 0; n < 4; ++n) \
        acc[(MBASE) + m][n] = __builtin_amdgcn_mfma_f32_16x16x32_bf16(af[m], bfr[n], acc[(MBASE) + m][n], 0, 0, 0); \
    __builtin_amdgcn_s_setprio(0);

#define KTILE(t, ISSUE, N1STR) { \
    const char* sa = ldsc + (((t) & 1) ? 65536u : 0u); \
    const char* sb = sa + 32768; \
    short8 bfr[4], af[4]; \
    /* ---- ph0: kk0, m0-3 ---- */ \
    asm volatile("s_waitcnt vmcnt(2)" ::: "memory"); \
    __builtin_amdgcn_s_barrier(); \
    if (ISSUE) ISSUE_B01((t) + 1); \
    _Pragma("unroll") for (int n = 0; n < 4; ++n) \
      bfr[n] = *(const short8*)(sb + (wc * 64 + n * 16 + arow) * 128 + (kq ^ rxor)); \
    _Pragma("unroll") for (int m = 0; m < 4; ++m) \
      af[m] = *(const short8*)(sa + (wr * 128 + m * 16 + arow) * 128 + (kq ^ rxor)); \
    MFMA16(0) \
    /* ---- ph1: kk0, m4-7 ---- */ \
    asm volatile("s_waitcnt vmcnt(" N1STR ")" ::: "memory"); \
    __builtin_amdgcn_s_barrier(); \
    if (ISSUE) ISSUE_B23((t) + 1); \
    _Pragma("unroll") for (int m = 0; m < 4; ++m) \
      af[m] = *(const short8*)(sa + (wr * 128 + 64 + m * 16 + arow) * 128 + (kq ^ rxor)); \
    MFMA16(4) \
    /* ---- ph2: kk1, m0-3 ---- */ \
    if (ISSUE) ISSUE_A02((t) + 1); \
    _Pragma("unroll") for (int n = 0; n < 4; ++n) \
      bfr[n] = *(const short8*)(sb + (wc * 64 + n * 16 + arow) * 128 + ((64 + kq) ^ rxor)); \
    _Pragma("unroll") for (int m = 0; m < 4; ++m) \
      af[m] = *(const short8*)(sa + (wr * 128 + m * 16 + arow) * 128 + ((64 + kq) ^ rxor)); \
    MFMA16(0) \
    /* ---- ph3: kk1, m4-7 ---- */ \
    if (ISSUE) ISSUE_A13((t) + 1); \
    _Pragma("unroll") for (int m = 0; m < 4; ++m) \
      af[m] = *(const short8*)(sa + (wr * 128 + 64 + m * 16 + arow) * 128 + ((64 + kq) ^ rxor)); \
    MFMA16(4) }

// bijective XCD swizzle (m204); nwg % 8 == 0 for both gemm grids
#define XCD_DECODE(NX, NY) \
  int nwg  = (NX) * (NY) * NE; \
  int flat = blockIdx.x + (NX) * (blockIdx.y + (NY) * blockIdx.z); \
  int qq   = nwg >> 3; \
  int wg   = (flat & 7) * qq + (flat >> 3); \
  int bx   = wg % (NX); \
  int rem  = wg / (NX); \
  int y    = rem % (NY); \
  int e    = rem / (NY);

// GEMM1: act[slot, i] = silu(gate) * up, gate/up from interleaved wgu
__global__ __launch_bounds__(512, 2) void gemm1_fast(
    const unsigned short* __restrict__ xb, const unsigned short* __restrict__ wgu,
    const int* __restrict__ counts, const int* __restrict__ offsets,
    const int* __restrict__ token_map, unsigned short* __restrict__ act)
{
  extern __shared__ char smem[];               // 131072 B
  char* ldsc = smem;

  XCD_DECODE(8, 22)
  int cnt = counts[e];
  int off = offsets[e];

  int tid  = threadIdx.x;
  int lane = tid & 63;
  int w    = tid >> 6;
  int wr   = w >> 2;                           // 0..1 (M half)
  int wc   = w & 3;                            // 0..3 (N quarter; 0,1=gate 2,3=up)

  int srow0 = tid >> 3;                        // 0..63
  int colE  = (((tid & 7) ^ ((tid >> 3) & 7)) << 3);
  int rxor  = (lane & 7) << 4;
  int arow  = lane & 15;
  int kq    = (lane >> 4) << 4;
  int prow  = (lane >> 4) << 2;

  for (int t0 = bx * 256; t0 < cnt; t0 += 2048) {
    const unsigned short* aS[4];
    const unsigned short* bS[4];
    #pragma unroll
    for (int j = 0; j < 4; ++j) {
      int row  = srow0 + 64 * j;
      int tr   = t0 + row;
      int slot = off + (tr < cnt ? tr : cnt - 1);
      aS[j] = xb  + (size_t)token_map[slot] * HD + colE;
      bS[j] = wgu + ((size_t)e * NID2 + (size_t)y * 256 + row) * HD + colE;
    }

    f32x4 zf = {0.f, 0.f, 0.f, 0.f};
    f32x4 acc[8][4];
    #pragma unroll
    for (int m = 0; m < 8; ++m)
      #pragma unroll
      for (int n = 0; n < 4; ++n) acc[m][n] = zf;

    // prologue: tile 0, need-order
    ISSUE_B01(0); ISSUE_B23(0); ISSUE_A02(0); ISSUE_A13(0);
    for (int t = 0; t < HD / 64 - 1; ++t) KTILE(t, true, "2");
    KTILE(HD / 64 - 1, false, "0");

    // ---- epilogue: up-waves publish acc via LDS; gate-waves fuse silu ----
    __syncthreads();
    float* xch = (float*)smem;                 // 4 regions x 32KB (128x64 f32)
    if (wc >= 2) {
      float* base = xch + (size_t)((wr * 2 + (wc - 2)) * 8192);
      #pragma unroll
      for (int m = 0; m < 8; ++m)
        #pragma unroll
        for (int n = 0; n < 4; ++n)
          #pragma unroll
          for (int r = 0; r < 4; ++r)
            base[(m * 16 + prow + r) * 64 + n * 16 + arow] = acc[m][n][r];
    }
    __syncthreads();
    if (wc < 2) {
      const float* base = xch + (size_t)((wr * 2 + wc) * 8192);
      int i0 = y * 128 + wc * 64;
      #pragma unroll
      for (int m = 0; m < 8; ++m) {
        #pragma unroll
        for (int r = 0; r < 4; ++r) {
          int row = wr * 128 + m * 16 + prow + r;
          int tr2 = t0 + row;
          if (tr2 >= cnt) continue;
          size_t ob = (size_t)(off + tr2) * ID + i0 + arow;
          #pragma unroll
          for (int n = 0; n < 4; ++n) {
            float g = acc[m][n][r];
            float u = base[(m * 16 + prow + r) * 64 + n * 16 + arow];
            float h = g * u / (1.f + __expf(-g));
            act[ob + n * 16] = f2bf(h);
          }
        }
      }
    }
    __syncthreads();
  }
}

// GEMM2: down[slot, h] = act @ w_down^T   (combine applies router weights)
__global__ __launch_bounds__(512, 2) void gemm2_fast(
    const unsigned short* __restrict__ act, const unsigned short* __restrict__ wdb,
    const int* __restrict__ counts, const int* __restrict__ offsets,
    float* __restrict__ down)
{
  extern __shared__ char smem[];
  char* ldsc = smem;

  XCD_DECODE(8, 4)
  int cnt = counts[e];
  int off = offsets[e];

  int tid  = threadIdx.x;
  int lane = tid & 63;
  int w    = tid >> 6;
  int wr   = w >> 2;
  int wc   = w & 3;

  int srow0 = tid >> 3;
  int colE  = (((tid & 7) ^ ((tid >> 3) & 7)) << 3);
  int rxor  = (lane & 7) << 4;
  int arow  = lane & 15;
  int kq    = (lane >> 4) << 4;
  int prow  = (lane >> 4) << 2;

  for (int t0 = bx * 256; t0 < cnt; t0 += 2048) {
    const unsigned short* aS[4];
    const unsigned short* bS[4];
    #pragma unroll
    for (int j = 0; j < 4; ++j) {
      int row  = srow0 + 64 * j;
      int tr   = t0 + row;
      int slot = off + (tr < cnt ? tr : cnt - 1);
      aS[j] = act + (size_t)slot * ID + colE;
      bS[j] = wdb + ((size_t)e * HD + (size_t)y * 256 + row) * ID + colE;
    }

    f32x4 zf = {0.f, 0.f, 0.f, 0.f};
    f32x4 acc[8][4];
    #pragma unroll
    for (int m = 0; m < 8; ++m)
      #pragma unroll
      for (int n = 0; n < 4; ++n) acc[m][n] = zf;

    ISSUE_B01(0); ISSUE_B23(0); ISSUE_A02(0); ISSUE_A13(0);
    for (int t = 0; t < ID / 64 - 1; ++t) KTILE(t, true, "2");
    KTILE(ID / 64 - 1, false, "0");

    #pragma unroll
    for (int m = 0; m < 8; ++m) {
      #pragma unroll
      for (int r = 0; r < 4; ++r) {
        int row = wr * 128 + m * 16 + prow + r;
        int tr2 = t0 + row;
        if (tr2 >= cnt) continue;
        float* ob = down + (size_t)(off + tr2) * HD + (size_t)y * 256 + wc * 64 + arow;
        #pragma unroll
        for (int n = 0; n < 4; ++n)
          ob[n * 16] = acc[m][n][r];
      }
    }
    __syncthreads();
  }
}

// ---------------- combine: out[t] = w0*down[s0] + w1*down[s1] ---------------
__global__ __launch_bounds__(256) void combine_kernel(
    const float* __restrict__ down, const float* __restrict__ slot_w,
    const int* __restrict__ tok2slot, float* __restrict__ out)
{
  int t   = blockIdx.x;
  int tid = threadIdx.x;
  int s0  = tok2slot[2 * t], s1 = tok2slot[2 * t + 1];
  float w0 = slot_w[s0], w1 = slot_w[s1];
  const float4* d0 = (const float4*)(down + (size_t)s0 * HD) + tid;
  const float4* d1 = (const float4*)(down + (size_t)s1 * HD) + tid;
  float4 a = *d0, b = *d1;
  float4 o;
  o.x = w0 * a.x + w1 * b.x;  o.y = w0 * a.y + w1 * b.y;
  o.z = w0 * a.z + w1 * b.z;  o.w = w0 * a.w + w1 * b.w;
  ((float4*)(out + (size_t)t * HD))[tid] = o;
}

// ---------------- launch ----------------------------------------------------
extern "C" void kernel_launch(void* const* d_in, const int* in_sizes, int n_in,
                              void* d_out, int out_size, void* d_ws, size_t ws_size,
                              hipStream_t stream) {
  const float* x        = (const float*)d_in[0];
  const float* w_router = (const float*)d_in[1];
  const float* w_gate   = (const float*)d_in[2];
  const float* w_up     = (const float*)d_in[3];
  const float* w_down   = (const float*)d_in[4];

  char* ws = (char*)d_ws;
  int*   top2i    = (int*)(ws + WS_TOP2I);
  float* top2w    = (float*)(ws + WS_TOP2W);
  int*   counts   = (int*)(ws + WS_CNT);
  int*   offsets  = (int*)(ws + WS_OFF);
  int*   cursors  = (int*)(ws + WS_CUR);
  int*   tmap     = (int*)(ws + WS_TMAP);
  float* slotw    = (float*)(ws + WS_SLOTW);
  int*   tok2slot = (int*)(ws + WS_T2S);
  unsigned short* xb  = (unsigned short*)(ws + WS_XB);
  unsigned short* wgu = (unsigned short*)(ws + WS_WGU);
  unsigned short* wdb = (unsigned short*)(ws + WS_WDB);
  unsigned short* act = (unsigned short*)(ws + WS_ACT);
  float*          down = (float*)(ws + WS_WGU);   // aliases wgu (dead after gemm1)

  hipFuncSetAttribute((const void*)gemm1_fast,
                      hipFuncAttributeMaxDynamicSharedMemorySize, 131072);
  hipFuncSetAttribute((const void*)gemm2_fast,
                      hipFuncAttributeMaxDynamicSharedMemorySize, 131072);

  router_kernel<<<TT / 4, 256, 0, stream>>>(x, w_router, top2i, top2w, xb);
  count_scan_kernel<<<1, 256, 0, stream>>>(top2i, counts, offsets, cursors);
  place_kernel<<<TT / 256, 256, 0, stream>>>(top2i, top2w, cursors, tmap, slotw, tok2slot);
  cvt_wgu_kernel<<<dim3(2816, NE), 256, 0, stream>>>(w_gate, w_up, wgu);
  cvt_bf16_kernel<<<11264, 256, 0, stream>>>(w_down, wdb, NE * HD * ID / 8);

  gemm1_fast<<<dim3(8, 22, NE), 512, 131072, stream>>>(xb, wgu, counts, offsets, tmap, act);
  gemm2_fast<<<dim3(8, 4, NE), 512, 131072, stream>>>(act, wdb, counts, offsets, down);
  combine_kernel<<<TT, 256, 0, stream>>>(down, slotw, tok2slot, (float*)d_out);
}